// Round 1
// baseline (1001.803 us; speedup 1.0000x reference)
//
#include <hip/hip_runtime.h>
#include <math.h>

#define NT 100000
#define NP 50000
#define NE 800000
#define H 128

#define CDIV(a,b) (((a)+(b)-1)/(b))

static __device__ __forceinline__ float dot4(float4 a, float4 b){
  return a.x*b.x + a.y*b.y + a.z*b.z + a.w*b.w;
}

// ---------- rank-1 helper vectors: u = e@W, w = b_emb@W + bias ----------
__global__ void kvec(const float* __restrict__ e, const float* __restrict__ be,
                     const float* __restrict__ W, const float* __restrict__ bias,
                     float* __restrict__ u, float* __restrict__ w){
  int j = threadIdx.x;
  float su = 0.f, sw = 0.f;
  for (int i = 0; i < H; ++i) {
    float wv = W[i*H + j];
    su += e[i]*wv;
    sw += be[i]*wv;
  }
  u[j] = su;
  w[j] = sw + bias[j];
}

// ---------- fp32 GEMM: Y[M,128] = X[M,128] @ W[128,128] + bias ----------
__launch_bounds__(512)
__global__ void gemm128(const float* __restrict__ X, const float* __restrict__ W,
                        const float* __restrict__ bias, float* __restrict__ Y, int M){
  __shared__ float Wl[H*H];        // 64 KB
  __shared__ float Xl[128][H];     // 64 KB
  int tid = threadIdx.x;
  for (int i = tid; i < H*H; i += 512) Wl[i] = W[i];
  int row0 = blockIdx.x * 128;
  for (int i = tid; i < 128*32; i += 512) {
    int r = i >> 5, c4 = (i & 31) << 2;
    int gr = row0 + r;
    float4 v = make_float4(0.f,0.f,0.f,0.f);
    if (gr < M) v = *(const float4*)&X[(size_t)gr*H + c4];
    *(float4*)&Xl[r][c4] = v;
  }
  __syncthreads();
  int tx = tid & 31;    // 4 output cols: tx*4
  int ty = tid >> 5;    // 8 rows: ty*8
  float acc[8][4];
  #pragma unroll
  for (int i=0;i<8;++i){acc[i][0]=0.f;acc[i][1]=0.f;acc[i][2]=0.f;acc[i][3]=0.f;}
  for (int k0 = 0; k0 < H; k0 += 4) {
    float4 w0 = *(float4*)&Wl[(k0+0)*H + tx*4];
    float4 w1 = *(float4*)&Wl[(k0+1)*H + tx*4];
    float4 w2 = *(float4*)&Wl[(k0+2)*H + tx*4];
    float4 w3 = *(float4*)&Wl[(k0+3)*H + tx*4];
    #pragma unroll
    for (int i = 0; i < 8; ++i) {
      float4 a = *(float4*)&Xl[ty*8+i][k0];
      acc[i][0] += a.x*w0.x + a.y*w1.x + a.z*w2.x + a.w*w3.x;
      acc[i][1] += a.x*w0.y + a.y*w1.y + a.z*w2.y + a.w*w3.y;
      acc[i][2] += a.x*w0.z + a.y*w1.z + a.z*w2.z + a.w*w3.z;
      acc[i][3] += a.x*w0.w + a.y*w1.w + a.z*w2.w + a.w*w3.w;
    }
  }
  float4 bv = *(const float4*)&bias[tx*4];
  #pragma unroll
  for (int i = 0; i < 8; ++i) {
    int gr = row0 + ty*8 + i;
    if (gr < M) {
      float4 o = make_float4(acc[i][0]+bv.x, acc[i][1]+bv.y, acc[i][2]+bv.z, acc[i][3]+bv.w);
      *(float4*)&Y[(size_t)gr*H + tx*4] = o;
    }
  }
}

// ---------- CSR build ----------
__global__ void kcount(const int* __restrict__ dst, int* __restrict__ deg, int n){
  int i = blockIdx.x*256 + threadIdx.x;
  if (i < n) atomicAdd(&deg[dst[i]], 1);
}
__global__ void kscatter(const int* __restrict__ dst, int* __restrict__ cursor,
                         int* __restrict__ eids, int n){
  int i = blockIdx.x*256 + threadIdx.x;
  if (i < n) { int pos = atomicAdd(&cursor[dst[i]], 1); eids[pos] = i; }
}
__global__ void kscan1(const int* __restrict__ in, int* __restrict__ out,
                       int* __restrict__ bsums, int n){
  __shared__ int sh[256];
  int t = threadIdx.x, i = blockIdx.x*256 + t;
  int v = (i<n)? in[i] : 0;
  sh[t] = v; __syncthreads();
  for (int off=1; off<256; off<<=1){
    int u = (t>=off)? sh[t-off] : 0;
    __syncthreads();
    sh[t] += u;
    __syncthreads();
  }
  if (i<n) out[i] = sh[t]-v;           // exclusive
  if (t==255) bsums[blockIdx.x] = sh[255];
}
__launch_bounds__(1024)
__global__ void kscan2(int* __restrict__ bsums, int n){
  __shared__ int sh[1024];
  int t = threadIdx.x;
  int v = (t<n)? bsums[t] : 0;
  sh[t] = v; __syncthreads();
  for (int off=1; off<1024; off<<=1){
    int u = (t>=off)? sh[t-off] : 0;
    __syncthreads();
    sh[t] += u;
    __syncthreads();
  }
  if (t<n) bsums[t] = sh[t]-v;         // exclusive
}
__global__ void kscanadd(int* __restrict__ out, const int* __restrict__ bsums, int n){
  int i = blockIdx.x*256 + threadIdx.x;
  if (i<n) out[i] += bsums[blockIdx.x];
}

// ---------- per-phrase dots: a[p] = q[p]·u, c[p] = q[p]·w ----------
__global__ void kdots(const float* __restrict__ Q, const float* __restrict__ u,
                      const float* __restrict__ w, float* __restrict__ a,
                      float* __restrict__ c, int n){
  int gid = (blockIdx.x*blockDim.x + threadIdx.x) >> 5;
  int lane = threadIdx.x & 31;
  if (gid >= n) return;
  float4 q  = *(const float4*)&Q[(size_t)gid*H + lane*4];
  float4 uu = *(const float4*)&u[lane*4];
  float4 ww = *(const float4*)&w[lane*4];
  float pa = dot4(q,uu), pc = dot4(q,ww);
  #pragma unroll
  for (int off=1; off<32; off<<=1){ pa += __shfl_xor(pa,off); pc += __shfl_xor(pc,off); }
  if (lane==0){ a[gid]=pa; c[gid]=pc; }
}

// ---------- beta gate + combine + optional leaky, write row ----------
static __device__ __forceinline__ void beta_combine(float4 o, float4 sk,
    const float* __restrict__ Wb, int lane, bool leaky, float* __restrict__ dstRow){
  float4 wb0 = *(const float4*)&Wb[lane*4];
  float4 wb1 = *(const float4*)&Wb[H   + lane*4];
  float4 wb2 = *(const float4*)&Wb[2*H + lane*4];
  float4 dv = make_float4(o.x-sk.x, o.y-sk.y, o.z-sk.z, o.w-sk.w);
  float part = dot4(o,wb0) + dot4(sk,wb1) + dot4(dv,wb2);
  #pragma unroll
  for (int off=1; off<32; off<<=1) part += __shfl_xor(part, off);
  float beta = 1.f/(1.f + __expf(-part));
  float4 r;
  r.x = beta*sk.x + (1.f-beta)*o.x;
  r.y = beta*sk.y + (1.f-beta)*o.y;
  r.z = beta*sk.z + (1.f-beta)*o.z;
  r.w = beta*sk.w + (1.f-beta)*o.w;
  if (leaky){
    r.x = r.x>0.f? r.x : 0.01f*r.x;
    r.y = r.y>0.f? r.y : 0.01f*r.y;
    r.z = r.z>0.f? r.z : 0.01f*r.z;
    r.w = r.w>0.f? r.w : 0.01f*r.w;
  }
  *(float4*)&dstRow[lane*4] = r;
}

// ---------- tconv1 (token->phrase): scalar online softmax per phrase ----------
__global__ void knode1(const int* __restrict__ rowptr, const int* __restrict__ deg,
                       const int* __restrict__ eids, const int* __restrict__ src,
                       const float* __restrict__ x_tok, const float* __restrict__ a1,
                       const float* __restrict__ c1, float* __restrict__ dden,
                       float* __restrict__ dsv, int n){
  int p = blockIdx.x*256 + threadIdx.x;
  if (p >= n) return;
  float a = a1[p], c = c1[p];
  int rp = rowptr[p], dg = deg[p];
  const float RS = 0.08838834764831845f;  // 1/sqrt(128)
  float m = -INFINITY, d = 0.f, sv = 0.f;
  for (int i = 0; i < dg; ++i) {
    int e = eids[rp+i];
    float x = x_tok[src[e]];
    float s = (x*a + c)*RS;
    if (s > m){ float sc = __expf(m - s); d *= sc; sv *= sc; m = s; }
    float pp = __expf(s - m);
    d += pp; sv += pp*x;
  }
  dden[p] = d; dsv[p] = sv;
}

__global__ void kcomb1(const float* __restrict__ dden, const float* __restrict__ dsv,
                       const float* __restrict__ uv, const float* __restrict__ wv,
                       const float* __restrict__ S, const float* __restrict__ Wb,
                       float* __restrict__ out, int n){
  int gid = (blockIdx.x*blockDim.x + threadIdx.x) >> 5;
  int lane = threadIdx.x & 31;
  if (gid >= n) return;
  float d = dden[gid], sv = dsv[gid];
  float inv = 1.f/(d + 1e-16f);
  float4 u4 = *(const float4*)&uv[lane*4];
  float4 w4 = *(const float4*)&wv[lane*4];
  float4 o = make_float4((sv*u4.x + d*w4.x)*inv, (sv*u4.y + d*w4.y)*inv,
                         (sv*u4.z + d*w4.z)*inv, (sv*u4.w + d*w4.w)*inv);
  float4 sk = *(const float4*)&S[(size_t)gid*H + lane*4];
  beta_combine(o, sk, Wb, lane, true, out + (size_t)gid*H);
}

// ---------- tconv2 (phrase->token, q/skip rank-1): fused node kernel ----------
__global__ void knode2(const float* __restrict__ x_tok, const float* __restrict__ ak,
                       const float* __restrict__ ck, const float* __restrict__ V,
                       const int* __restrict__ rowptr, const int* __restrict__ deg,
                       const int* __restrict__ eids, const int* __restrict__ src,
                       const float* __restrict__ us, const float* __restrict__ ws,
                       const float* __restrict__ Wb, float* __restrict__ out, int n){
  int gid = (blockIdx.x*blockDim.x + threadIdx.x) >> 5;
  int lane = threadIdx.x & 31;
  if (gid >= n) return;
  float xt = x_tok[gid];
  int rp = rowptr[gid], dg = deg[gid];
  const float RS = 0.08838834764831845f;
  float m = -INFINITY, d = 0.f;
  float4 acc = make_float4(0.f,0.f,0.f,0.f);
  for (int i = 0; i < dg; ++i) {
    int e  = eids[rp+i];
    int sp = src[e];
    float s = (xt*ak[sp] + ck[sp])*RS;
    float4 v = *(const float4*)&V[(size_t)sp*H + lane*4];
    if (s > m){
      float sc = __expf(m - s);
      d *= sc; acc.x *= sc; acc.y *= sc; acc.z *= sc; acc.w *= sc;
      m = s;
    }
    float pp = __expf(s - m);
    d += pp;
    acc.x += pp*v.x; acc.y += pp*v.y; acc.z += pp*v.z; acc.w += pp*v.w;
  }
  float inv = 1.f/(d + 1e-16f);
  float4 o = make_float4(acc.x*inv, acc.y*inv, acc.z*inv, acc.w*inv);
  float4 u4 = *(const float4*)&us[lane*4];
  float4 w4 = *(const float4*)&ws[lane*4];
  float4 sk = make_float4(xt*u4.x+w4.x, xt*u4.y+w4.y, xt*u4.z+w4.z, xt*u4.w+w4.w);
  beta_combine(o, sk, Wb, lane, true, out + (size_t)gid*H);
}

// ---------- tconv3 (p1->t1, full q/k/v/skip): fused node kernel ----------
__global__ void knode3(const float* __restrict__ Q, const float* __restrict__ K,
                       const float* __restrict__ V, const float* __restrict__ S,
                       const int* __restrict__ rowptr, const int* __restrict__ deg,
                       const int* __restrict__ eids, const int* __restrict__ src,
                       const float* __restrict__ Wb, float* __restrict__ out, int n){
  int gid = (blockIdx.x*blockDim.x + threadIdx.x) >> 5;
  int lane = threadIdx.x & 31;
  if (gid >= n) return;
  float4 q = *(const float4*)&Q[(size_t)gid*H + lane*4];
  int rp = rowptr[gid], dg = deg[gid];
  const float RS = 0.08838834764831845f;
  float m = -INFINITY, d = 0.f;
  float4 acc = make_float4(0.f,0.f,0.f,0.f);
  for (int i = 0; i < dg; ++i) {
    int e  = eids[rp+i];
    int sp = src[e];
    float4 kk = *(const float4*)&K[(size_t)sp*H + lane*4];
    float ps = dot4(q, kk);
    #pragma unroll
    for (int off=1; off<32; off<<=1) ps += __shfl_xor(ps, off);
    float s = ps*RS;
    float4 v = *(const float4*)&V[(size_t)sp*H + lane*4];
    if (s > m){
      float sc = __expf(m - s);
      d *= sc; acc.x *= sc; acc.y *= sc; acc.z *= sc; acc.w *= sc;
      m = s;
    }
    float pp = __expf(s - m);
    d += pp;
    acc.x += pp*v.x; acc.y += pp*v.y; acc.z += pp*v.z; acc.w += pp*v.w;
  }
  float inv = 1.f/(d + 1e-16f);
  float4 o = make_float4(acc.x*inv, acc.y*inv, acc.z*inv, acc.w*inv);
  float4 sk = *(const float4*)&S[(size_t)gid*H + lane*4];
  beta_combine(o, sk, Wb, lane, false, out + (size_t)gid*H);  // no leaky on t2
}

extern "C" void kernel_launch(void* const* d_in, const int* in_sizes, int n_in,
                              void* d_out, int out_size, void* d_ws, size_t ws_size,
                              hipStream_t stream){
  const float* x_token  = (const float*)d_in[0];
  const float* x_phrase = (const float*)d_in[1];
  const float* W_emb    = (const float*)d_in[2];
  const float* b_emb    = (const float*)d_in[3];
  const float* Wq_tp = (const float*)d_in[4];  const float* bq_tp = (const float*)d_in[5];
  const float* Wk_tp = (const float*)d_in[6];  const float* bk_tp = (const float*)d_in[7];
  const float* Wv_tp = (const float*)d_in[8];  const float* bv_tp = (const float*)d_in[9];
  const float* Ws_tp = (const float*)d_in[10]; const float* bs_tp = (const float*)d_in[11];
  const float* Wb_tp = (const float*)d_in[12];
  const float* Wq_pt = (const float*)d_in[13]; const float* bq_pt = (const float*)d_in[14];
  const float* Wk_pt = (const float*)d_in[15]; const float* bk_pt = (const float*)d_in[16];
  const float* Wv_pt = (const float*)d_in[17]; const float* bv_pt = (const float*)d_in[18];
  const float* Ws_pt = (const float*)d_in[19]; const float* bs_pt = (const float*)d_in[20];
  const float* Wb_pt = (const float*)d_in[21];
  const float* W_head = (const float*)d_in[22]; const float* b_head = (const float*)d_in[23];
  const int* src_tp = (const int*)d_in[24];
  const int* dst_tp = (const int*)d_in[25];
  const int* src_pt = (const int*)d_in[26];
  const int* dst_pt = (const int*)d_in[27];
  float* out = (float*)d_out;

  // ---- workspace carve (~240 MB) ----
  char* base = (char*)d_ws;
  size_t off = 0;
  auto AF = [&](size_t n)->float*{ float* p=(float*)(base+off); off += ((n+3)&~(size_t)3)*4; return p; };
  auto AI = [&](size_t n)->int*  { int*   p=(int*)  (base+off); off += ((n+3)&~(size_t)3)*4; return p; };
  float* A  = AF((size_t)NP*H);   // q1 / k2 / k3
  float* B  = AF((size_t)NP*H);   // s1 / v2 / v3
  float* P1 = AF((size_t)NP*H);   // p1
  float* C  = AF((size_t)NT*H);   // q3
  float* D  = AF((size_t)NT*H);   // s3
  float* T1 = AF((size_t)NT*H);   // t1, then t2
  float* vecs = AF(8*H);
  float* uk1=vecs, *wk1=vecs+H, *uv1=vecs+2*H, *wv1=vecs+3*H;
  float* uq2=vecs+4*H, *wq2=vecs+5*H, *us2=vecs+6*H, *ws2=vecs+7*H;
  float* a1   = AF(NP); float* c1  = AF(NP);
  float* dden = AF(NP); float* dsv = AF(NP);
  int* degP = AI(NP); int* rowP = AI(NP); int* curP = AI(NP); int* eidsP = AI(NE);
  int* degT = AI(NT); int* rowT = AI(NT); int* curT = AI(NT); int* eidsT = AI(NE);
  int* bsums = AI(1024);
  (void)ws_size; (void)in_sizes; (void)n_in; (void)out_size;

  const int nbP = CDIV(NP,256), nbT = CDIV(NT,256), nbE = CDIV(NE,256);

  // rank-1 helper vectors
  kvec<<<1,H,0,stream>>>(W_emb,b_emb,Wk_tp,bk_tp,uk1,wk1);
  kvec<<<1,H,0,stream>>>(W_emb,b_emb,Wv_tp,bv_tp,uv1,wv1);
  kvec<<<1,H,0,stream>>>(W_emb,b_emb,Wq_pt,bq_pt,uq2,wq2);
  kvec<<<1,H,0,stream>>>(W_emb,b_emb,Ws_pt,bs_pt,us2,ws2);

  // CSR for dst_tp (phrase segments)
  hipMemsetAsync(degP, 0, (size_t)NP*4, stream);
  kcount<<<nbE,256,0,stream>>>(dst_tp, degP, NE);
  kscan1<<<nbP,256,0,stream>>>(degP, rowP, bsums, NP);
  kscan2<<<1,1024,0,stream>>>(bsums, nbP);
  kscanadd<<<nbP,256,0,stream>>>(rowP, bsums, NP);
  hipMemcpyAsync(curP, rowP, (size_t)NP*4, hipMemcpyDeviceToDevice, stream);
  kscatter<<<nbE,256,0,stream>>>(dst_tp, curP, eidsP, NE);

  // tconv1: q1, s1 GEMMs; phrase dots; scalar node pass; combine -> p1
  gemm128<<<CDIV(NP,128),512,0,stream>>>(x_phrase, Wq_tp, bq_tp, A, NP);
  gemm128<<<CDIV(NP,128),512,0,stream>>>(x_phrase, Ws_tp, bs_tp, B, NP);
  kdots<<<CDIV(NP*32,256),256,0,stream>>>(A, uk1, wk1, a1, c1, NP);
  knode1<<<nbP,256,0,stream>>>(rowP, degP, eidsP, src_tp, x_token, a1, c1, dden, dsv, NP);
  kcomb1<<<CDIV(NP*32,256),256,0,stream>>>(dden, dsv, uv1, wv1, B, Wb_tp, P1, NP);

  // CSR for dst_pt (token segments) — shared by tconv2 & tconv3
  hipMemsetAsync(degT, 0, (size_t)NT*4, stream);
  kcount<<<nbE,256,0,stream>>>(dst_pt, degT, NE);
  kscan1<<<nbT,256,0,stream>>>(degT, rowT, bsums, NT);
  kscan2<<<1,1024,0,stream>>>(bsums, nbT);
  kscanadd<<<nbT,256,0,stream>>>(rowT, bsums, NT);
  hipMemcpyAsync(curT, rowT, (size_t)NT*4, hipMemcpyDeviceToDevice, stream);
  kscatter<<<nbE,256,0,stream>>>(dst_pt, curT, eidsT, NE);

  // tconv2: k2, v2 GEMMs; phrase dots vs rank-1 q; fused node kernel -> t1
  gemm128<<<CDIV(NP,128),512,0,stream>>>(x_phrase, Wk_pt, bk_pt, A, NP);
  gemm128<<<CDIV(NP,128),512,0,stream>>>(x_phrase, Wv_pt, bv_pt, B, NP);
  kdots<<<CDIV(NP*32,256),256,0,stream>>>(A, uq2, wq2, a1, c1, NP);
  knode2<<<CDIV(NT*32,256),256,0,stream>>>(x_token, a1, c1, B, rowT, degT, eidsT, src_pt,
                                           us2, ws2, Wb_pt, T1, NT);

  // tconv3: q3,s3 from t1; k3,v3 from p1; fused node kernel -> t2 (into T1)
  gemm128<<<CDIV(NT,128),512,0,stream>>>(T1, Wq_pt, bq_pt, C, NT);
  gemm128<<<CDIV(NT,128),512,0,stream>>>(T1, Ws_pt, bs_pt, D, NT);
  gemm128<<<CDIV(NP,128),512,0,stream>>>(P1, Wk_pt, bk_pt, A, NP);
  gemm128<<<CDIV(NP,128),512,0,stream>>>(P1, Wv_pt, bv_pt, B, NP);
  knode3<<<CDIV(NT*32,256),256,0,stream>>>(C, A, B, D, rowT, degT, eidsT, src_pt,
                                           Wb_pt, T1, NT);

  // head
  gemm128<<<CDIV(NT,128),512,0,stream>>>(T1, W_head, b_head, out, NT);
}

// Round 2
// 852.396 us; speedup vs baseline: 1.1753x; 1.1753x over previous
//
#include <hip/hip_runtime.h>
#include <math.h>

#define NT 100000
#define NP 50000
#define NE 800000
#define H 128

#define CDIV(a,b) (((a)+(b)-1)/(b))

static __device__ __forceinline__ float dot4(float4 a, float4 b){
  return a.x*b.x + a.y*b.y + a.z*b.z + a.w*b.w;
}
static __device__ __forceinline__ float b2f(unsigned short u){
  union { unsigned int i; float f; } c; c.i = ((unsigned int)u) << 16; return c.f;
}
static __device__ __forceinline__ unsigned short f2b(float f){
  union { float f; unsigned int i; } c; c.f = f;
  unsigned int x = c.i;
  unsigned int r = (x + 0x7fffu + ((x >> 16) & 1u)) >> 16;   // RNE
  return (unsigned short)r;
}

// ---------- rank-1 helper vectors: u = e@W, w = b_emb@W + bias (4 sets) ----------
__global__ void kvec4(const float* __restrict__ e, const float* __restrict__ be,
    const float* W0, const float* bi0, float* u0, float* w0,
    const float* W1, const float* bi1, float* u1, float* w1,
    const float* W2, const float* bi2, float* u2, float* w2,
    const float* W3, const float* bi3, float* u3, float* w3){
  const float *W, *bi; float *u, *w;
  switch (blockIdx.x){
    case 0: W=W0; bi=bi0; u=u0; w=w0; break;
    case 1: W=W1; bi=bi1; u=u1; w=w1; break;
    case 2: W=W2; bi=bi2; u=u2; w=w2; break;
    default:W=W3; bi=bi3; u=u3; w=w3; break;
  }
  int j = threadIdx.x;
  float su = 0.f, sw = 0.f;
  for (int i = 0; i < H; ++i) {
    float wv = W[i*H + j];
    su += e[i]*wv;
    sw += be[i]*wv;
  }
  u[j] = su;
  w[j] = sw + bi[j];
}

// ---------- paired fp32 GEMM: Y1 = X@W1+b1 (or fused rank-1 dots), Y2 = X@W2+b2 ----------
template<bool BF>
static __device__ __forceinline__ void store_row4(void* Y, int ld, int of, int gr, int col, float4 o){
  if constexpr (BF){
    unsigned short* p = (unsigned short*)Y + (size_t)gr*ld + of + col;
    ushort4 h; h.x=f2b(o.x); h.y=f2b(o.y); h.z=f2b(o.z); h.w=f2b(o.w);
    *(ushort4*)p = h;
  } else {
    float* p = (float*)Y + (size_t)gr*ld + of + col;
    *(float4*)p = o;
  }
}

static __device__ __forceinline__ void compute_pass(const float* Wl, const float (*Xl)[H],
                                                    int tx, int ty, float acc[8][4]){
  #pragma unroll
  for (int i=0;i<8;++i){acc[i][0]=0.f;acc[i][1]=0.f;acc[i][2]=0.f;acc[i][3]=0.f;}
  for (int k0 = 0; k0 < H; k0 += 4) {
    float4 w0 = *(const float4*)&Wl[(k0+0)*H + tx*4];
    float4 w1 = *(const float4*)&Wl[(k0+1)*H + tx*4];
    float4 w2 = *(const float4*)&Wl[(k0+2)*H + tx*4];
    float4 w3 = *(const float4*)&Wl[(k0+3)*H + tx*4];
    #pragma unroll
    for (int i = 0; i < 8; ++i) {
      float4 a = *(const float4*)&Xl[ty*8+i][k0];
      acc[i][0] += a.x*w0.x + a.y*w1.x + a.z*w2.x + a.w*w3.x;
      acc[i][1] += a.x*w0.y + a.y*w1.y + a.z*w2.y + a.w*w3.y;
      acc[i][2] += a.x*w0.z + a.y*w1.z + a.z*w2.z + a.w*w3.z;
      acc[i][3] += a.x*w0.w + a.y*w1.w + a.z*w2.w + a.w*w3.w;
    }
  }
}

template<int DOTS1, int B1, int B2>
__launch_bounds__(512)
__global__ void gemm_pair(const float* __restrict__ X, int M,
    const float* __restrict__ W1, const float* __restrict__ b1,
    void* __restrict__ Y1, int ld1, int of1,
    const float* __restrict__ uvec, const float* __restrict__ wvec,
    float* __restrict__ aout, float* __restrict__ cout,
    const float* __restrict__ W2, const float* __restrict__ b2,
    void* __restrict__ Y2, int ld2, int of2){
  __shared__ float Wl[H*H];        // 64 KB
  __shared__ float Xl[128][H];     // 64 KB
  int tid = threadIdx.x;
  // prefetch W2 into registers (latency hidden under pass 1)
  float4 w2r[8];
  #pragma unroll
  for (int i = 0; i < 8; ++i) w2r[i] = *(const float4*)&W2[(i*512 + tid)*4];
  for (int i = tid; i < H*H; i += 512) Wl[i] = W1[i];
  int row0 = blockIdx.x * 128;
  for (int i = tid; i < 128*32; i += 512) {
    int r = i >> 5, c4 = (i & 31) << 2;
    int gr = row0 + r;
    float4 v = make_float4(0.f,0.f,0.f,0.f);
    if (gr < M) v = *(const float4*)&X[(size_t)gr*H + c4];
    *(float4*)&Xl[r][c4] = v;
  }
  __syncthreads();
  int tx = tid & 31, ty = tid >> 5;
  float acc[8][4];

  // ---- pass 1: W1 ----
  compute_pass(Wl, Xl, tx, ty, acc);
  {
    float4 bv = *(const float4*)&b1[tx*4];
    if constexpr (DOTS1){
      float4 u4 = *(const float4*)&uvec[tx*4];
      float4 w4 = *(const float4*)&wvec[tx*4];
      #pragma unroll
      for (int i = 0; i < 8; ++i) {
        int gr = row0 + ty*8 + i;
        float4 o = make_float4(acc[i][0]+bv.x, acc[i][1]+bv.y, acc[i][2]+bv.z, acc[i][3]+bv.w);
        float pa = dot4(o,u4), pc = dot4(o,w4);
        #pragma unroll
        for (int off=1; off<32; off<<=1){ pa += __shfl_xor(pa,off); pc += __shfl_xor(pc,off); }
        if (tx == 0 && gr < M){ aout[gr] = pa; cout[gr] = pc; }
      }
    } else {
      #pragma unroll
      for (int i = 0; i < 8; ++i) {
        int gr = row0 + ty*8 + i;
        if (gr < M) {
          float4 o = make_float4(acc[i][0]+bv.x, acc[i][1]+bv.y, acc[i][2]+bv.z, acc[i][3]+bv.w);
          store_row4<B1>(Y1, ld1, of1, gr, tx*4, o);
        }
      }
    }
  }
  __syncthreads();
  #pragma unroll
  for (int i = 0; i < 8; ++i) *(float4*)&Wl[(i*512 + tid)*4] = w2r[i];
  __syncthreads();

  // ---- pass 2: W2 ----
  compute_pass(Wl, Xl, tx, ty, acc);
  {
    float4 bv = *(const float4*)&b2[tx*4];
    #pragma unroll
    for (int i = 0; i < 8; ++i) {
      int gr = row0 + ty*8 + i;
      if (gr < M) {
        float4 o = make_float4(acc[i][0]+bv.x, acc[i][1]+bv.y, acc[i][2]+bv.z, acc[i][3]+bv.w);
        store_row4<B2>(Y2, ld2, of2, gr, tx*4, o);
      }
    }
  }
}

// ---------- single fp32 GEMM (head) ----------
__launch_bounds__(512)
__global__ void gemm128(const float* __restrict__ X, const float* __restrict__ W,
                        const float* __restrict__ bias, float* __restrict__ Y, int M){
  __shared__ float Wl[H*H];
  __shared__ float Xl[128][H];
  int tid = threadIdx.x;
  for (int i = tid; i < H*H; i += 512) Wl[i] = W[i];
  int row0 = blockIdx.x * 128;
  for (int i = tid; i < 128*32; i += 512) {
    int r = i >> 5, c4 = (i & 31) << 2;
    int gr = row0 + r;
    float4 v = make_float4(0.f,0.f,0.f,0.f);
    if (gr < M) v = *(const float4*)&X[(size_t)gr*H + c4];
    *(float4*)&Xl[r][c4] = v;
  }
  __syncthreads();
  int tx = tid & 31, ty = tid >> 5;
  float acc[8][4];
  compute_pass(Wl, Xl, tx, ty, acc);
  float4 bv = *(const float4*)&bias[tx*4];
  #pragma unroll
  for (int i = 0; i < 8; ++i) {
    int gr = row0 + ty*8 + i;
    if (gr < M) {
      float4 o = make_float4(acc[i][0]+bv.x, acc[i][1]+bv.y, acc[i][2]+bv.z, acc[i][3]+bv.w);
      *(float4*)&Y[(size_t)gr*H + tx*4] = o;
    }
  }
}

// ---------- CSR build ----------
__global__ void kcount(const int* __restrict__ dst, int* __restrict__ deg, int n){
  int i = blockIdx.x*256 + threadIdx.x;
  if (i < n) atomicAdd(&deg[dst[i]], 1);
}
// scatter the SOURCE INDEX directly (kills one indirection in node kernels)
__global__ void kscat_src(const int* __restrict__ dst, const int* __restrict__ src,
                          int* __restrict__ cursor, int* __restrict__ srcs, int n){
  int i = blockIdx.x*256 + threadIdx.x;
  if (i < n) { int pos = atomicAdd(&cursor[dst[i]], 1); srcs[pos] = src[i]; }
}
// scatter the gathered scalar VALUE directly (token->phrase edges need only x_token[src])
__global__ void kscat_val(const int* __restrict__ dst, const int* __restrict__ src,
                          const float* __restrict__ xv, int* __restrict__ cursor,
                          float* __restrict__ vals, int n){
  int i = blockIdx.x*256 + threadIdx.x;
  if (i < n) { int pos = atomicAdd(&cursor[dst[i]], 1); vals[pos] = xv[src[i]]; }
}
__global__ void kscan1(const int* __restrict__ in, int* __restrict__ out,
                       int* __restrict__ bsums, int n){
  __shared__ int sh[256];
  int t = threadIdx.x, i = blockIdx.x*256 + t;
  int v = (i<n)? in[i] : 0;
  sh[t] = v; __syncthreads();
  for (int off=1; off<256; off<<=1){
    int u = (t>=off)? sh[t-off] : 0;
    __syncthreads();
    sh[t] += u;
    __syncthreads();
  }
  if (i<n) out[i] = sh[t]-v;
  if (t==255) bsums[blockIdx.x] = sh[255];
}
__launch_bounds__(1024)
__global__ void kscan2(int* __restrict__ bsums, int n){
  __shared__ int sh[1024];
  int t = threadIdx.x;
  int v = (t<n)? bsums[t] : 0;
  sh[t] = v; __syncthreads();
  for (int off=1; off<1024; off<<=1){
    int u = (t>=off)? sh[t-off] : 0;
    __syncthreads();
    sh[t] += u;
    __syncthreads();
  }
  if (t<n) bsums[t] = sh[t]-v;
}
__global__ void kscanadd(int* __restrict__ out, const int* __restrict__ bsums, int n){
  int i = blockIdx.x*256 + threadIdx.x;
  if (i<n) out[i] += bsums[blockIdx.x];
}

// ---------- beta gate + combine + optional leaky ----------
static __device__ __forceinline__ void beta_combine(float4 o, float4 sk,
    const float* __restrict__ Wb, int lane, bool leaky, float* __restrict__ dstRow){
  float4 wb0 = *(const float4*)&Wb[lane*4];
  float4 wb1 = *(const float4*)&Wb[H   + lane*4];
  float4 wb2 = *(const float4*)&Wb[2*H + lane*4];
  float4 dv = make_float4(o.x-sk.x, o.y-sk.y, o.z-sk.z, o.w-sk.w);
  float part = dot4(o,wb0) + dot4(sk,wb1) + dot4(dv,wb2);
  #pragma unroll
  for (int off=1; off<32; off<<=1) part += __shfl_xor(part, off);
  float beta = 1.f/(1.f + __expf(-part));
  float4 r;
  r.x = beta*sk.x + (1.f-beta)*o.x;
  r.y = beta*sk.y + (1.f-beta)*o.y;
  r.z = beta*sk.z + (1.f-beta)*o.z;
  r.w = beta*sk.w + (1.f-beta)*o.w;
  if (leaky){
    r.x = r.x>0.f? r.x : 0.01f*r.x;
    r.y = r.y>0.f? r.y : 0.01f*r.y;
    r.z = r.z>0.f? r.z : 0.01f*r.z;
    r.w = r.w>0.f? r.w : 0.01f*r.w;
  }
  *(float4*)&dstRow[lane*4] = r;
}

// ---------- tconv1 (token->phrase): scalar online softmax per phrase ----------
__global__ void knode1(const int* __restrict__ rowptr, const int* __restrict__ deg,
                       const float* __restrict__ vals,
                       const float* __restrict__ a1, const float* __restrict__ c1,
                       float* __restrict__ dden, float* __restrict__ dsv, int n){
  int p = blockIdx.x*256 + threadIdx.x;
  if (p >= n) return;
  float a = a1[p], c = c1[p];
  int rp = rowptr[p], dg = deg[p];
  const float RS = 0.08838834764831845f;
  float m = -INFINITY, d = 0.f, sv = 0.f;
  for (int i = 0; i < dg; ++i) {
    float x = vals[rp+i];
    float s = (x*a + c)*RS;
    if (s > m){ float sc = __expf(m - s); d *= sc; sv *= sc; m = s; }
    float pp = __expf(s - m);
    d += pp; sv += pp*x;
  }
  dden[p] = d; dsv[p] = sv;
}

__global__ void kcomb1(const float* __restrict__ dden, const float* __restrict__ dsv,
                       const float* __restrict__ uv, const float* __restrict__ wv,
                       const float* __restrict__ S, const float* __restrict__ Wb,
                       float* __restrict__ out, int n){
  int gid = (blockIdx.x*blockDim.x + threadIdx.x) >> 5;
  int lane = threadIdx.x & 31;
  if (gid >= n) return;
  float d = dden[gid], sv = dsv[gid];
  float inv = 1.f/(d + 1e-16f);
  float4 u4 = *(const float4*)&uv[lane*4];
  float4 w4 = *(const float4*)&wv[lane*4];
  float4 o = make_float4((sv*u4.x + d*w4.x)*inv, (sv*u4.y + d*w4.y)*inv,
                         (sv*u4.z + d*w4.z)*inv, (sv*u4.w + d*w4.w)*inv);
  float4 sk = *(const float4*)&S[(size_t)gid*H + lane*4];
  beta_combine(o, sk, Wb, lane, true, out + (size_t)gid*H);
}

// ---------- tconv2 (phrase->token): bf16 V gather ----------
__global__ void knode2(const float* __restrict__ x_tok, const float* __restrict__ ak,
                       const float* __restrict__ ck, const unsigned short* __restrict__ Vb,
                       const int* __restrict__ rowptr, const int* __restrict__ deg,
                       const int* __restrict__ srcs,
                       const float* __restrict__ us, const float* __restrict__ ws,
                       const float* __restrict__ Wb, float* __restrict__ out, int n){
  int gid = (blockIdx.x*blockDim.x + threadIdx.x) >> 5;
  int lane = threadIdx.x & 31;
  if (gid >= n) return;
  float xt = x_tok[gid];
  int rp = rowptr[gid], dg = deg[gid];
  const float RS = 0.08838834764831845f;
  float m = -INFINITY, d = 0.f;
  float4 acc = make_float4(0.f,0.f,0.f,0.f);
  for (int i = 0; i < dg; ++i) {
    int sp = srcs[rp+i];
    float s = (xt*ak[sp] + ck[sp])*RS;
    ushort4 hv = *(const ushort4*)(Vb + (size_t)sp*H + lane*4);
    float4 v = make_float4(b2f(hv.x), b2f(hv.y), b2f(hv.z), b2f(hv.w));
    if (s > m){
      float sc = __expf(m - s);
      d *= sc; acc.x *= sc; acc.y *= sc; acc.z *= sc; acc.w *= sc;
      m = s;
    }
    float pp = __expf(s - m);
    d += pp;
    acc.x += pp*v.x; acc.y += pp*v.y; acc.z += pp*v.z; acc.w += pp*v.w;
  }
  float inv = 1.f/(d + 1e-16f);
  float4 o = make_float4(acc.x*inv, acc.y*inv, acc.z*inv, acc.w*inv);
  float4 u4 = *(const float4*)&us[lane*4];
  float4 w4 = *(const float4*)&ws[lane*4];
  float4 sk = make_float4(xt*u4.x+w4.x, xt*u4.y+w4.y, xt*u4.z+w4.z, xt*u4.w+w4.w);
  beta_combine(o, sk, Wb, lane, true, out + (size_t)gid*H);
}

// ---------- tconv3: interleaved bf16 KV gather ----------
__global__ void knode3(const float* __restrict__ Q, const unsigned short* __restrict__ KV,
                       const float* __restrict__ S,
                       const int* __restrict__ rowptr, const int* __restrict__ deg,
                       const int* __restrict__ srcs,
                       const float* __restrict__ Wb, float* __restrict__ out, int n){
  int gid = (blockIdx.x*blockDim.x + threadIdx.x) >> 5;
  int lane = threadIdx.x & 31;
  if (gid >= n) return;
  float4 q = *(const float4*)&Q[(size_t)gid*H + lane*4];
  int rp = rowptr[gid], dg = deg[gid];
  const float RS = 0.08838834764831845f;
  float m = -INFINITY, d = 0.f;
  float4 acc = make_float4(0.f,0.f,0.f,0.f);
  for (int i = 0; i < dg; ++i) {
    int sp = srcs[rp+i];
    const ushort4* kvp = (const ushort4*)(KV + (size_t)sp*256);
    ushort4 hk = kvp[lane];
    ushort4 hv = kvp[32 + lane];
    float4 kk = make_float4(b2f(hk.x), b2f(hk.y), b2f(hk.z), b2f(hk.w));
    float ps = dot4(q, kk);
    #pragma unroll
    for (int off=1; off<32; off<<=1) ps += __shfl_xor(ps, off);
    float s = ps*RS;
    float4 v = make_float4(b2f(hv.x), b2f(hv.y), b2f(hv.z), b2f(hv.w));
    if (s > m){
      float sc = __expf(m - s);
      d *= sc; acc.x *= sc; acc.y *= sc; acc.z *= sc; acc.w *= sc;
      m = s;
    }
    float pp = __expf(s - m);
    d += pp;
    acc.x += pp*v.x; acc.y += pp*v.y; acc.z += pp*v.z; acc.w += pp*v.w;
  }
  float inv = 1.f/(d + 1e-16f);
  float4 o = make_float4(acc.x*inv, acc.y*inv, acc.z*inv, acc.w*inv);
  float4 sk = *(const float4*)&S[(size_t)gid*H + lane*4];
  beta_combine(o, sk, Wb, lane, false, out + (size_t)gid*H);
}

extern "C" void kernel_launch(void* const* d_in, const int* in_sizes, int n_in,
                              void* d_out, int out_size, void* d_ws, size_t ws_size,
                              hipStream_t stream){
  const float* x_token  = (const float*)d_in[0];
  const float* x_phrase = (const float*)d_in[1];
  const float* W_emb    = (const float*)d_in[2];
  const float* b_emb    = (const float*)d_in[3];
  const float* Wq_tp = (const float*)d_in[4];  const float* bq_tp = (const float*)d_in[5];
  const float* Wk_tp = (const float*)d_in[6];  const float* bk_tp = (const float*)d_in[7];
  const float* Wv_tp = (const float*)d_in[8];  const float* bv_tp = (const float*)d_in[9];
  const float* Ws_tp = (const float*)d_in[10]; const float* bs_tp = (const float*)d_in[11];
  const float* Wb_tp = (const float*)d_in[12];
  const float* Wq_pt = (const float*)d_in[13]; const float* bq_pt = (const float*)d_in[14];
  const float* Wk_pt = (const float*)d_in[15]; const float* bk_pt = (const float*)d_in[16];
  const float* Wv_pt = (const float*)d_in[17]; const float* bv_pt = (const float*)d_in[18];
  const float* Ws_pt = (const float*)d_in[19]; const float* bs_pt = (const float*)d_in[20];
  const float* Wb_pt = (const float*)d_in[21];
  const float* W_head = (const float*)d_in[22]; const float* b_head = (const float*)d_in[23];
  const int* src_tp = (const int*)d_in[24];
  const int* dst_tp = (const int*)d_in[25];
  const int* src_pt = (const int*)d_in[26];
  const int* dst_pt = (const int*)d_in[27];
  float* out = (float*)d_out;

  // ---- workspace carve ----
  char* base = (char*)d_ws;
  size_t off = 0;
  auto AF = [&](size_t n)->float*{ float* p=(float*)(base+off); off += ((n+3)&~(size_t)3)*4; return p; };
  auto AI = [&](size_t n)->int*  { int*   p=(int*)  (base+off); off += ((n+3)&~(size_t)3)*4; return p; };
  float* B  = AF((size_t)NP*H);   // s1; later overlaid by KVb (bf16 [NP][256])
  float* P1 = AF((size_t)NP*H);   // p1
  float* C  = AF((size_t)NT*H);   // Vb (bf16 [NP][128]) early, q3 later
  float* D  = AF((size_t)NT*H);   // s3
  float* T1 = AF((size_t)NT*H);   // t1, then t2
  unsigned short* Vb  = (unsigned short*)C;   // [NP][128] bf16, dead before q3 write
  unsigned short* KVb = (unsigned short*)B;   // [NP][256] bf16 interleaved k3|v3, dead before... s1 consumed first
  float* vecs = AF(8*H);
  float* uk1=vecs, *wk1=vecs+H, *uv1=vecs+2*H, *wv1=vecs+3*H;
  float* uq2=vecs+4*H, *wq2=vecs+5*H, *us2=vecs+6*H, *ws2=vecs+7*H;
  float* a1   = AF(NP); float* c1  = AF(NP);
  float* dden = AF(NP); float* dsv = AF(NP);
  int* degP = AI(NP); int* rowP = AI(NP); int* curP = AI(NP); float* valsP = AF(NE);
  int* degT = AI(NT); int* rowT = AI(NT); int* curT = AI(NT); int*   srcsT = AI(NE);
  int* bsums = AI(1024);
  (void)ws_size; (void)in_sizes; (void)n_in; (void)out_size;

  const int nbP = CDIV(NP,256), nbT = CDIV(NT,256), nbE = CDIV(NE,256);

  // rank-1 helper vectors (4 sets, one launch)
  kvec4<<<4,H,0,stream>>>(W_emb, b_emb,
      Wk_tp, bk_tp, uk1, wk1,
      Wv_tp, bv_tp, uv1, wv1,
      Wq_pt, bq_pt, uq2, wq2,
      Ws_pt, bs_pt, us2, ws2);

  // CSR for dst_tp (phrase segments) — store gathered x values directly
  hipMemsetAsync(degP, 0, (size_t)NP*4, stream);
  kcount<<<nbE,256,0,stream>>>(dst_tp, degP, NE);
  kscan1<<<nbP,256,0,stream>>>(degP, rowP, bsums, NP);
  kscan2<<<1,1024,0,stream>>>(bsums, nbP);
  kscanadd<<<nbP,256,0,stream>>>(rowP, bsums, NP);
  hipMemcpyAsync(curP, rowP, (size_t)NP*4, hipMemcpyDeviceToDevice, stream);
  kscat_val<<<nbE,256,0,stream>>>(dst_tp, src_tp, x_token, curP, valsP, NE);

  // CSR for dst_pt (token segments) — store source phrase ids directly
  hipMemsetAsync(degT, 0, (size_t)NT*4, stream);
  kcount<<<nbE,256,0,stream>>>(dst_pt, degT, NE);
  kscan1<<<nbT,256,0,stream>>>(degT, rowT, bsums, NT);
  kscan2<<<1,1024,0,stream>>>(bsums, nbT);
  kscanadd<<<nbT,256,0,stream>>>(rowT, bsums, NT);
  hipMemcpyAsync(curT, rowT, (size_t)NT*4, hipMemcpyDeviceToDevice, stream);
  kscat_src<<<nbE,256,0,stream>>>(dst_pt, src_pt, curT, srcsT, NE);

  // tconv1: pass1 = q1 (fused dots -> a1,c1, not materialized), pass2 = s1 -> B
  gemm_pair<1,0,0><<<CDIV(NP,128),512,0,stream>>>(x_phrase, NP,
      Wq_tp, bq_tp, nullptr, 0, 0, uk1, wk1, a1, c1,
      Ws_tp, bs_tp, B, H, 0);
  knode1<<<nbP,256,0,stream>>>(rowP, degP, valsP, a1, c1, dden, dsv, NP);
  kcomb1<<<CDIV(NP*32,256),256,0,stream>>>(dden, dsv, uv1, wv1, B, Wb_tp, P1, NP);

  // tconv2: pass1 = k2 (fused dots vs rank-1 q2 -> a1,c1), pass2 = v2 -> Vb (bf16)
  gemm_pair<1,0,1><<<CDIV(NP,128),512,0,stream>>>(x_phrase, NP,
      Wk_pt, bk_pt, nullptr, 0, 0, uq2, wq2, a1, c1,
      Wv_pt, bv_pt, Vb, H, 0);
  knode2<<<CDIV(NT*32,256),256,0,stream>>>(x_token, a1, c1, Vb, rowT, degT, srcsT,
                                           us2, ws2, Wb_pt, T1, NT);

  // tconv3: q3,s3 from t1 (fp32); k3,v3 from p1 -> interleaved bf16 KV
  gemm_pair<0,0,0><<<CDIV(NT,128),512,0,stream>>>(T1, NT,
      Wq_pt, bq_pt, C, H, 0, nullptr, nullptr, nullptr, nullptr,
      Ws_pt, bs_pt, D, H, 0);
  gemm_pair<0,1,1><<<CDIV(NP,128),512,0,stream>>>(P1, NP,
      Wk_pt, bk_pt, KVb, 256, 0, nullptr, nullptr, nullptr, nullptr,
      Wv_pt, bv_pt, KVb, 256, H);
  knode3<<<CDIV(NT*32,256),256,0,stream>>>(C, KVb, D, rowT, degT, srcsT,
                                           Wb_pt, T1, NT);

  // head
  gemm128<<<CDIV(NT,128),512,0,stream>>>(T1, W_head, b_head, out, NT);
}

// Round 3
// 533.886 us; speedup vs baseline: 1.8764x; 1.5966x over previous
//
#include <hip/hip_runtime.h>
#include <math.h>

#define NT 100000
#define NP 50000
#define NE 800000
#define H 128

#define CDIV(a,b) (((a)+(b)-1)/(b))

typedef __attribute__((ext_vector_type(8))) short s16x8;
typedef __attribute__((ext_vector_type(4))) short s16x4;
typedef __attribute__((ext_vector_type(4))) float f32x4;

static __device__ __forceinline__ float dot4(float4 a, float4 b){
  return a.x*b.x + a.y*b.y + a.z*b.z + a.w*b.w;
}
static __device__ __forceinline__ float b2f(unsigned short u){
  union { unsigned int i; float f; } c; c.i = ((unsigned int)u) << 16; return c.f;
}
static __device__ __forceinline__ unsigned short f2b(float f){
  union { float f; unsigned int i; } c; c.f = f;
  unsigned int x = c.i;
  unsigned int r = (x + 0x7fffu + ((x >> 16) & 1u)) >> 16;   // RNE
  return (unsigned short)r;
}

// ---------- rank-1 helper vectors ----------
__global__ void kvec4(const float* __restrict__ e, const float* __restrict__ be,
    const float* W0, const float* bi0, float* u0, float* w0,
    const float* W1, const float* bi1, float* u1, float* w1,
    const float* W2, const float* bi2, float* u2, float* w2,
    const float* W3, const float* bi3, float* u3, float* w3){
  const float *W, *bi; float *u, *w;
  switch (blockIdx.x){
    case 0: W=W0; bi=bi0; u=u0; w=w0; break;
    case 1: W=W1; bi=bi1; u=u1; w=w1; break;
    case 2: W=W2; bi=bi2; u=u2; w=w2; break;
    default:W=W3; bi=bi3; u=u3; w=w3; break;
  }
  int j = threadIdx.x;
  float su = 0.f, sw = 0.f;
  for (int i = 0; i < H; ++i) {
    float wv = W[i*H + j];
    su += e[i]*wv;
    sw += be[i]*wv;
  }
  u[j] = su;
  w[j] = sw + bi[j];
}

// ---------- MFMA GEMM, bf16x3 split (fp32-accurate) ----------
// Block: 256 thr (4 waves), 128 rows. Wave w: rows [w*32, w*32+32).
// W staged transposed+split in LDS (hi/lo bf16, XOR-swizzled 16B chunks).
// A frags from global (coalesced), kept in regs across both passes.

static __device__ __forceinline__ void stage_w(const float* __restrict__ W,
    unsigned short* __restrict__ WH, unsigned short* __restrict__ WL, int tid){
  #pragma unroll
  for (int it = 0; it < 16; ++it){
    int gid = it*256 + tid;
    int n  = gid & 127;          // output col -> WT row
    int kg = gid >> 7;           // 0..31, group of 4 consecutive k
    int k0 = kg*4;
    float w0 = W[(k0+0)*H + n];
    float w1 = W[(k0+1)*H + n];
    float w2 = W[(k0+2)*H + n];
    float w3 = W[(k0+3)*H + n];
    unsigned short h0=f2b(w0), h1=f2b(w1), h2=f2b(w2), h3=f2b(w3);
    s16x4 hv; hv[0]=(short)h0; hv[1]=(short)h1; hv[2]=(short)h2; hv[3]=(short)h3;
    s16x4 lv; lv[0]=(short)f2b(w0-b2f(h0)); lv[1]=(short)f2b(w1-b2f(h1));
              lv[2]=(short)f2b(w2-b2f(h2)); lv[3]=(short)f2b(w3-b2f(h3));
    int base = n*128 + (((kg>>1) ^ (n&15))<<3) + ((kg&1)<<2);
    *(s16x4*)(WH + base) = hv;
    *(s16x4*)(WL + base) = lv;
  }
}

#define MFMA_PASS(ACC)                                                          \
  {                                                                             \
    _Pragma("unroll")                                                           \
    for (int g = 0; g < 2; ++g){                                                \
      _Pragma("unroll")                                                         \
      for (int t = 0; t < 8; ++t){ ACC[g][t][0]=0.f;ACC[g][t][1]=0.f;ACC[g][t][2]=0.f;ACC[g][t][3]=0.f; } \
    }                                                                           \
    _Pragma("unroll")                                                           \
    for (int s = 0; s < 4; ++s){                                                \
      _Pragma("unroll")                                                         \
      for (int t = 0; t < 8; ++t){                                              \
        int n = t*16 + l15;                                                     \
        int off = n*128 + (((s*4 + l4) ^ l15)<<3);                              \
        s16x8 BH = *(const s16x8*)(WH + off);                                   \
        s16x8 BL = *(const s16x8*)(WL + off);                                   \
        _Pragma("unroll")                                                       \
        for (int g = 0; g < 2; ++g){                                            \
          ACC[g][t] = __builtin_amdgcn_mfma_f32_16x16x32_bf16(AH[g][s], BH, ACC[g][t], 0,0,0); \
          ACC[g][t] = __builtin_amdgcn_mfma_f32_16x16x32_bf16(AH[g][s], BL, ACC[g][t], 0,0,0); \
          ACC[g][t] = __builtin_amdgcn_mfma_f32_16x16x32_bf16(AL[g][s], BH, ACC[g][t], 0,0,0); \
        }                                                                       \
      }                                                                         \
    }                                                                           \
  }

#define EPI_WRITE(ACC, BIAS)                                                    \
  {                                                                             \
    float bb[8];                                                                \
    _Pragma("unroll")                                                           \
    for (int t = 0; t < 8; ++t) bb[t] = BIAS[t*16 + l15];                       \
    _Pragma("unroll")                                                           \
    for (int g = 0; g < 2; ++g){                                                \
      _Pragma("unroll")                                                         \
      for (int t = 0; t < 8; ++t){                                              \
        _Pragma("unroll")                                                       \
        for (int r = 0; r < 4; ++r)                                             \
          EPI[w*32 + g*16 + l4*4 + r][t*16 + l15] = ACC[g][t][r] + bb[t];       \
      }                                                                         \
    }                                                                           \
  }

template<int BF>
static __device__ __forceinline__ void epi_store(void* Y, int ld, int of, int row0, int M,
                                                 int tid, const float (*EPI)[132]){
  #pragma unroll
  for (int it = 0; it < 16; ++it){
    int fid = it*256 + tid;
    int r = fid >> 5, c4 = (fid & 31) << 2;
    int grow = row0 + r;
    if (grow < M){
      float4 v = *(const float4*)&EPI[r][c4];
      if constexpr (BF){
        ushort4 hv; hv.x=f2b(v.x); hv.y=f2b(v.y); hv.z=f2b(v.z); hv.w=f2b(v.w);
        *(ushort4*)((unsigned short*)Y + (size_t)grow*ld + of + c4) = hv;
      } else {
        *(float4*)((float*)Y + (size_t)grow*ld + of + c4) = v;
      }
    }
  }
}

template<int DOTS1, int B1, int B2, int TWO>
__launch_bounds__(256)
__global__ void mgemm(const float* __restrict__ X, int M,
    const float* __restrict__ W1, const float* __restrict__ b1,
    void* __restrict__ Y1, int ld1, int of1,
    const float* __restrict__ uvec, const float* __restrict__ wvec,
    float* __restrict__ aout, float* __restrict__ cout,
    const float* __restrict__ W2, const float* __restrict__ b2,
    void* __restrict__ Y2, int ld2, int of2){
  __shared__ __align__(16) char smem[128*132*4];
  unsigned short* WH = (unsigned short*)smem;
  unsigned short* WL = WH + 16384;
  float (*EPI)[132] = (float(*)[132])smem;

  int tid = threadIdx.x;
  int lane = tid & 63, w = tid >> 6;
  int l15 = lane & 15, l4 = lane >> 4;
  int row0 = blockIdx.x * 128;

  // ---- load all A fragments (2 row-groups x 4 ksteps), hi/lo split ----
  s16x8 AH[2][4], AL[2][4];
  #pragma unroll
  for (int g = 0; g < 2; ++g){
    int row = row0 + w*32 + g*16 + l15;
    const float* xr = X + (size_t)row*H;
    bool ok = row < M;
    #pragma unroll
    for (int s = 0; s < 4; ++s){
      int kb = s*32 + l4*8;
      float4 f0 = ok ? *(const float4*)(xr+kb)   : make_float4(0.f,0.f,0.f,0.f);
      float4 f1 = ok ? *(const float4*)(xr+kb+4) : make_float4(0.f,0.f,0.f,0.f);
      float xs[8] = {f0.x,f0.y,f0.z,f0.w,f1.x,f1.y,f1.z,f1.w};
      s16x8 h, lo;
      #pragma unroll
      for (int e = 0; e < 8; ++e){
        unsigned short hh = f2b(xs[e]);
        h[e]  = (short)hh;
        lo[e] = (short)f2b(xs[e] - b2f(hh));
      }
      AH[g][s] = h; AL[g][s] = lo;
    }
  }

  stage_w(W1, WH, WL, tid);
  __syncthreads();

  f32x4 acc[2][8];
  MFMA_PASS(acc);

  if constexpr (DOTS1){
    // fused rank-1 dots: a[row]=dot(y,u), c[row]=dot(y,w); y never materialized
    float ub[8], wb[8], bb[8];
    #pragma unroll
    for (int t = 0; t < 8; ++t){
      ub[t]=uvec[t*16+l15]; wb[t]=wvec[t*16+l15]; bb[t]=b1[t*16+l15];
    }
    #pragma unroll
    for (int g = 0; g < 2; ++g){
      #pragma unroll
      for (int r = 0; r < 4; ++r){
        float pa = 0.f, pc = 0.f;
        #pragma unroll
        for (int t = 0; t < 8; ++t){
          float y = acc[g][t][r] + bb[t];
          pa += y*ub[t]; pc += y*wb[t];
        }
        #pragma unroll
        for (int o = 1; o < 16; o <<= 1){ pa += __shfl_xor(pa,o); pc += __shfl_xor(pc,o); }
        int row = row0 + w*32 + g*16 + l4*4 + r;
        if (l15 == 0 && row < M){ aout[row] = pa; cout[row] = pc; }
      }
    }
  } else {
    __syncthreads();            // all waves done reading WT
    EPI_WRITE(acc, b1);
    __syncthreads();
    epi_store<B1>(Y1, ld1, of1, row0, M, tid, EPI);
  }

  if constexpr (TWO){
    __syncthreads();            // EPI/WT reads done
    stage_w(W2, WH, WL, tid);
    __syncthreads();
    f32x4 acc2[2][8];
    MFMA_PASS(acc2);
    __syncthreads();
    EPI_WRITE(acc2, b2);
    __syncthreads();
    epi_store<B2>(Y2, ld2, of2, row0, M, tid, EPI);
  }
}

// ---------- CSR build ----------
__global__ void kcount(const int* __restrict__ dst, int* __restrict__ deg, int n){
  int i = blockIdx.x*256 + threadIdx.x;
  if (i < n) atomicAdd(&deg[dst[i]], 1);
}
__global__ void kscat_src(const int* __restrict__ dst, const int* __restrict__ src,
                          int* __restrict__ cursor, int* __restrict__ srcs, int n){
  int i = blockIdx.x*256 + threadIdx.x;
  if (i < n) { int pos = atomicAdd(&cursor[dst[i]], 1); srcs[pos] = src[i]; }
}
__global__ void kscat_val(const int* __restrict__ dst, const int* __restrict__ src,
                          const float* __restrict__ xv, int* __restrict__ cursor,
                          float* __restrict__ vals, int n){
  int i = blockIdx.x*256 + threadIdx.x;
  if (i < n) { int pos = atomicAdd(&cursor[dst[i]], 1); vals[pos] = xv[src[i]]; }
}
__global__ void kscan1(const int* __restrict__ in, int* __restrict__ out,
                       int* __restrict__ bsums, int n){
  __shared__ int sh[256];
  int t = threadIdx.x, i = blockIdx.x*256 + t;
  int v = (i<n)? in[i] : 0;
  sh[t] = v; __syncthreads();
  for (int off=1; off<256; off<<=1){
    int u = (t>=off)? sh[t-off] : 0;
    __syncthreads();
    sh[t] += u;
    __syncthreads();
  }
  if (i<n) out[i] = sh[t]-v;
  if (t==255) bsums[blockIdx.x] = sh[255];
}
__launch_bounds__(1024)
__global__ void kscan2(int* __restrict__ bsums, int n){
  __shared__ int sh[1024];
  int t = threadIdx.x;
  int v = (t<n)? bsums[t] : 0;
  sh[t] = v; __syncthreads();
  for (int off=1; off<1024; off<<=1){
    int u = (t>=off)? sh[t-off] : 0;
    __syncthreads();
    sh[t] += u;
    __syncthreads();
  }
  if (t<n) bsums[t] = sh[t]-v;
}
__global__ void kscanadd(int* __restrict__ out, const int* __restrict__ bsums, int n){
  int i = blockIdx.x*256 + threadIdx.x;
  if (i<n) out[i] += bsums[blockIdx.x];
}

// ---------- beta gate + combine + optional leaky ----------
static __device__ __forceinline__ void beta_combine(float4 o, float4 sk,
    const float* __restrict__ Wb, int lane, bool leaky, float* __restrict__ dstRow){
  float4 wb0 = *(const float4*)&Wb[lane*4];
  float4 wb1 = *(const float4*)&Wb[H   + lane*4];
  float4 wb2 = *(const float4*)&Wb[2*H + lane*4];
  float4 dv = make_float4(o.x-sk.x, o.y-sk.y, o.z-sk.z, o.w-sk.w);
  float part = dot4(o,wb0) + dot4(sk,wb1) + dot4(dv,wb2);
  #pragma unroll
  for (int off=1; off<32; off<<=1) part += __shfl_xor(part, off);
  float beta = 1.f/(1.f + __expf(-part));
  float4 r;
  r.x = beta*sk.x + (1.f-beta)*o.x;
  r.y = beta*sk.y + (1.f-beta)*o.y;
  r.z = beta*sk.z + (1.f-beta)*o.z;
  r.w = beta*sk.w + (1.f-beta)*o.w;
  if (leaky){
    r.x = r.x>0.f? r.x : 0.01f*r.x;
    r.y = r.y>0.f? r.y : 0.01f*r.y;
    r.z = r.z>0.f? r.z : 0.01f*r.z;
    r.w = r.w>0.f? r.w : 0.01f*r.w;
  }
  *(float4*)&dstRow[lane*4] = r;
}

// ---------- tconv1 ----------
__global__ void knode1(const int* __restrict__ rowptr, const int* __restrict__ deg,
                       const float* __restrict__ vals,
                       const float* __restrict__ a1, const float* __restrict__ c1,
                       float* __restrict__ dden, float* __restrict__ dsv, int n){
  int p = blockIdx.x*256 + threadIdx.x;
  if (p >= n) return;
  float a = a1[p], c = c1[p];
  int rp = rowptr[p], dg = deg[p];
  const float RS = 0.08838834764831845f;
  float m = -INFINITY, d = 0.f, sv = 0.f;
  for (int i = 0; i < dg; ++i) {
    float x = vals[rp+i];
    float s = (x*a + c)*RS;
    if (s > m){ float sc = __expf(m - s); d *= sc; sv *= sc; m = s; }
    float pp = __expf(s - m);
    d += pp; sv += pp*x;
  }
  dden[p] = d; dsv[p] = sv;
}

__global__ void kcomb1(const float* __restrict__ dden, const float* __restrict__ dsv,
                       const float* __restrict__ uv, const float* __restrict__ wv,
                       const float* __restrict__ S, const float* __restrict__ Wb,
                       float* __restrict__ out, int n){
  int gid = (blockIdx.x*blockDim.x + threadIdx.x) >> 5;
  int lane = threadIdx.x & 31;
  if (gid >= n) return;
  float d = dden[gid], sv = dsv[gid];
  float inv = 1.f/(d + 1e-16f);
  float4 u4 = *(const float4*)&uv[lane*4];
  float4 w4 = *(const float4*)&wv[lane*4];
  float4 o = make_float4((sv*u4.x + d*w4.x)*inv, (sv*u4.y + d*w4.y)*inv,
                         (sv*u4.z + d*w4.z)*inv, (sv*u4.w + d*w4.w)*inv);
  float4 sk = *(const float4*)&S[(size_t)gid*H + lane*4];
  beta_combine(o, sk, Wb, lane, true, out + (size_t)gid*H);
}

// ---------- tconv2 ----------
__global__ void knode2(const float* __restrict__ x_tok, const float* __restrict__ ak,
                       const float* __restrict__ ck, const unsigned short* __restrict__ Vb,
                       const int* __restrict__ rowptr, const int* __restrict__ deg,
                       const int* __restrict__ srcs,
                       const float* __restrict__ us, const float* __restrict__ ws,
                       const float* __restrict__ Wb, float* __restrict__ out, int n){
  int gid = (blockIdx.x*blockDim.x + threadIdx.x) >> 5;
  int lane = threadIdx.x & 31;
  if (gid >= n) return;
  float xt = x_tok[gid];
  int rp = rowptr[gid], dg = deg[gid];
  const float RS = 0.08838834764831845f;
  float m = -INFINITY, d = 0.f;
  float4 acc = make_float4(0.f,0.f,0.f,0.f);
  for (int i = 0; i < dg; ++i) {
    int sp = srcs[rp+i];
    float s = (xt*ak[sp] + ck[sp])*RS;
    ushort4 hv = *(const ushort4*)(Vb + (size_t)sp*H + lane*4);
    float4 v = make_float4(b2f(hv.x), b2f(hv.y), b2f(hv.z), b2f(hv.w));
    if (s > m){
      float sc = __expf(m - s);
      d *= sc; acc.x *= sc; acc.y *= sc; acc.z *= sc; acc.w *= sc;
      m = s;
    }
    float pp = __expf(s - m);
    d += pp;
    acc.x += pp*v.x; acc.y += pp*v.y; acc.z += pp*v.z; acc.w += pp*v.w;
  }
  float inv = 1.f/(d + 1e-16f);
  float4 o = make_float4(acc.x*inv, acc.y*inv, acc.z*inv, acc.w*inv);
  float4 u4 = *(const float4*)&us[lane*4];
  float4 w4 = *(const float4*)&ws[lane*4];
  float4 sk = make_float4(xt*u4.x+w4.x, xt*u4.y+w4.y, xt*u4.z+w4.z, xt*u4.w+w4.w);
  beta_combine(o, sk, Wb, lane, true, out + (size_t)gid*H);
}

// ---------- tconv3 ----------
__global__ void knode3(const float* __restrict__ Q, const unsigned short* __restrict__ KV,
                       const float* __restrict__ S,
                       const int* __restrict__ rowptr, const int* __restrict__ deg,
                       const int* __restrict__ srcs,
                       const float* __restrict__ Wb, float* __restrict__ out, int n){
  int gid = (blockIdx.x*blockDim.x + threadIdx.x) >> 5;
  int lane = threadIdx.x & 31;
  if (gid >= n) return;
  float4 q = *(const float4*)&Q[(size_t)gid*H + lane*4];
  int rp = rowptr[gid], dg = deg[gid];
  const float RS = 0.08838834764831845f;
  float m = -INFINITY, d = 0.f;
  float4 acc = make_float4(0.f,0.f,0.f,0.f);
  for (int i = 0; i < dg; ++i) {
    int sp = srcs[rp+i];
    const ushort4* kvp = (const ushort4*)(KV + (size_t)sp*256);
    ushort4 hk = kvp[lane];
    ushort4 hv = kvp[32 + lane];
    float4 kk = make_float4(b2f(hk.x), b2f(hk.y), b2f(hk.z), b2f(hk.w));
    float ps = dot4(q, kk);
    #pragma unroll
    for (int off=1; off<32; off<<=1) ps += __shfl_xor(ps, off);
    float s = ps*RS;
    float4 v = make_float4(b2f(hv.x), b2f(hv.y), b2f(hv.z), b2f(hv.w));
    if (s > m){
      float sc = __expf(m - s);
      d *= sc; acc.x *= sc; acc.y *= sc; acc.z *= sc; acc.w *= sc;
      m = s;
    }
    float pp = __expf(s - m);
    d += pp;
    acc.x += pp*v.x; acc.y += pp*v.y; acc.z += pp*v.z; acc.w += pp*v.w;
  }
  float inv = 1.f/(d + 1e-16f);
  float4 o = make_float4(acc.x*inv, acc.y*inv, acc.z*inv, acc.w*inv);
  float4 sk = *(const float4*)&S[(size_t)gid*H + lane*4];
  beta_combine(o, sk, Wb, lane, false, out + (size_t)gid*H);
}

extern "C" void kernel_launch(void* const* d_in, const int* in_sizes, int n_in,
                              void* d_out, int out_size, void* d_ws, size_t ws_size,
                              hipStream_t stream){
  const float* x_token  = (const float*)d_in[0];
  const float* x_phrase = (const float*)d_in[1];
  const float* W_emb    = (const float*)d_in[2];
  const float* b_emb    = (const float*)d_in[3];
  const float* Wq_tp = (const float*)d_in[4];  const float* bq_tp = (const float*)d_in[5];
  const float* Wk_tp = (const float*)d_in[6];  const float* bk_tp = (const float*)d_in[7];
  const float* Wv_tp = (const float*)d_in[8];  const float* bv_tp = (const float*)d_in[9];
  const float* Ws_tp = (const float*)d_in[10]; const float* bs_tp = (const float*)d_in[11];
  const float* Wb_tp = (const float*)d_in[12];
  const float* Wq_pt = (const float*)d_in[13]; const float* bq_pt = (const float*)d_in[14];
  const float* Wk_pt = (const float*)d_in[15]; const float* bk_pt = (const float*)d_in[16];
  const float* Wv_pt = (const float*)d_in[17]; const float* bv_pt = (const float*)d_in[18];
  const float* Ws_pt = (const float*)d_in[19]; const float* bs_pt = (const float*)d_in[20];
  const float* Wb_pt = (const float*)d_in[21];
  const float* W_head = (const float*)d_in[22]; const float* b_head = (const float*)d_in[23];
  const int* src_tp = (const int*)d_in[24];
  const int* dst_tp = (const int*)d_in[25];
  const int* src_pt = (const int*)d_in[26];
  const int* dst_pt = (const int*)d_in[27];
  float* out = (float*)d_out;

  // ---- workspace carve ----
  char* base = (char*)d_ws;
  size_t off = 0;
  auto AF = [&](size_t n)->float*{ float* p=(float*)(base+off); off += ((n+3)&~(size_t)3)*4; return p; };
  auto AI = [&](size_t n)->int*  { int*   p=(int*)  (base+off); off += ((n+3)&~(size_t)3)*4; return p; };
  float* B  = AF((size_t)NP*H);   // s1 fp32; later overlaid by KVb (bf16 [NP][256])
  float* P1 = AF((size_t)NP*H);   // p1
  float* C  = AF((size_t)NT*H);   // Vb (bf16) early, q3 later
  float* D  = AF((size_t)NT*H);   // s3
  float* T1 = AF((size_t)NT*H);   // t1, then t2
  unsigned short* Vb  = (unsigned short*)C;
  unsigned short* KVb = (unsigned short*)B;
  float* vecs = AF(8*H);
  float* uk1=vecs, *wk1=vecs+H, *uv1=vecs+2*H, *wv1=vecs+3*H;
  float* uq2=vecs+4*H, *wq2=vecs+5*H, *us2=vecs+6*H, *ws2=vecs+7*H;
  float* a1   = AF(NP); float* c1  = AF(NP);
  float* dden = AF(NP); float* dsv = AF(NP);
  int* degP = AI(NP); int* rowP = AI(NP); int* curP = AI(NP); float* valsP = AF(NE);
  int* degT = AI(NT); int* rowT = AI(NT); int* curT = AI(NT); int*   srcsT = AI(NE);
  int* bsums = AI(1024);
  (void)ws_size; (void)in_sizes; (void)n_in; (void)out_size;

  const int nbP = CDIV(NP,256), nbT = CDIV(NT,256), nbE = CDIV(NE,256);
  const int gP = CDIV(NP,128), gT = CDIV(NT,128);

  kvec4<<<4,H,0,stream>>>(W_emb, b_emb,
      Wk_tp, bk_tp, uk1, wk1,
      Wv_tp, bv_tp, uv1, wv1,
      Wq_pt, bq_pt, uq2, wq2,
      Ws_pt, bs_pt, us2, ws2);

  // CSR for dst_tp (phrase segments) — store gathered x values directly
  hipMemsetAsync(degP, 0, (size_t)NP*4, stream);
  kcount<<<nbE,256,0,stream>>>(dst_tp, degP, NE);
  kscan1<<<nbP,256,0,stream>>>(degP, rowP, bsums, NP);
  kscan2<<<1,1024,0,stream>>>(bsums, nbP);
  kscanadd<<<nbP,256,0,stream>>>(rowP, bsums, NP);
  hipMemcpyAsync(curP, rowP, (size_t)NP*4, hipMemcpyDeviceToDevice, stream);
  kscat_val<<<nbE,256,0,stream>>>(dst_tp, src_tp, x_token, curP, valsP, NE);

  // CSR for dst_pt (token segments)
  hipMemsetAsync(degT, 0, (size_t)NT*4, stream);
  kcount<<<nbE,256,0,stream>>>(dst_pt, degT, NE);
  kscan1<<<nbT,256,0,stream>>>(degT, rowT, bsums, NT);
  kscan2<<<1,1024,0,stream>>>(bsums, nbT);
  kscanadd<<<nbT,256,0,stream>>>(rowT, bsums, NT);
  hipMemcpyAsync(curT, rowT, (size_t)NT*4, hipMemcpyDeviceToDevice, stream);
  kscat_src<<<nbE,256,0,stream>>>(dst_pt, src_pt, curT, srcsT, NE);

  // tconv1: pass1 = q1 (fused dots -> a1,c1), pass2 = s1 -> B (fp32)
  mgemm<1,0,0,1><<<gP,256,0,stream>>>(x_phrase, NP,
      Wq_tp, bq_tp, nullptr, 0, 0, uk1, wk1, a1, c1,
      Ws_tp, bs_tp, B, H, 0);
  knode1<<<nbP,256,0,stream>>>(rowP, degP, valsP, a1, c1, dden, dsv, NP);
  kcomb1<<<CDIV(NP*32,256),256,0,stream>>>(dden, dsv, uv1, wv1, B, Wb_tp, P1, NP);

  // tconv2: pass1 = k2 (fused dots vs rank-1 q2), pass2 = v2 -> Vb (bf16)
  mgemm<1,0,1,1><<<gP,256,0,stream>>>(x_phrase, NP,
      Wk_pt, bk_pt, nullptr, 0, 0, uq2, wq2, a1, c1,
      Wv_pt, bv_pt, Vb, H, 0);
  knode2<<<CDIV(NT*32,256),256,0,stream>>>(x_token, a1, c1, Vb, rowT, degT, srcsT,
                                           us2, ws2, Wb_pt, T1, NT);

  // tconv3: q3,s3 from t1 (fp32); k3,v3 from p1 -> interleaved bf16 KV
  mgemm<0,0,0,1><<<gT,256,0,stream>>>(T1, NT,
      Wq_pt, bq_pt, C, H, 0, nullptr, nullptr, nullptr, nullptr,
      Ws_pt, bs_pt, D, H, 0);
  mgemm<0,1,1,1><<<gP,256,0,stream>>>(P1, NP,
      Wk_pt, bk_pt, KVb, 256, 0, nullptr, nullptr, nullptr, nullptr,
      Wv_pt, bv_pt, KVb, 256, H);
  knode3<<<CDIV(NT*32,256),256,0,stream>>>(C, KVb, D, rowT, degT, srcsT,
                                           Wb_pt, T1, NT);

  // head (single pass)
  mgemm<0,0,0,0><<<gT,256,0,stream>>>(T1, NT,
      W_head, b_head, out, H, 0, nullptr, nullptr, nullptr, nullptr,
      nullptr, nullptr, nullptr, 0, 0);
}

// Round 5
// 494.602 us; speedup vs baseline: 2.0255x; 1.0794x over previous
//
#include <hip/hip_runtime.h>
#include <math.h>

#define NT 100000
#define NP 50000
#define NE 800000
#define H 128

#define CDIV(a,b) (((a)+(b)-1)/(b))

typedef __attribute__((ext_vector_type(8))) short s16x8;
typedef __attribute__((ext_vector_type(4))) short s16x4;
typedef __attribute__((ext_vector_type(4))) unsigned short u16x4;
typedef __attribute__((ext_vector_type(4))) float f32x4;

static __device__ __forceinline__ float dot4(float4 a, float4 b){
  return a.x*b.x + a.y*b.y + a.z*b.z + a.w*b.w;
}
static __device__ __forceinline__ float b2f(unsigned short u){
  union { unsigned int i; float f; } c; c.i = ((unsigned int)u) << 16; return c.f;
}
static __device__ __forceinline__ unsigned short f2b(float f){
  union { float f; unsigned int i; } c; c.f = f;
  unsigned int x = c.i;
  unsigned int r = (x + 0x7fffu + ((x >> 16) & 1u)) >> 16;   // RNE
  return (unsigned short)r;
}
static __device__ __forceinline__ float4 cvt4(ushort4 h){
  return make_float4(b2f(h.x), b2f(h.y), b2f(h.z), b2f(h.w));
}
static __device__ __forceinline__ float4 cvt4u(u16x4 h){
  return make_float4(b2f(h[0]), b2f(h[1]), b2f(h[2]), b2f(h[3]));
}

// ---------- rank-1 helper vectors ----------
__global__ void kvec4(const float* __restrict__ e, const float* __restrict__ be,
    const float* W0, const float* bi0, float* u0, float* w0,
    const float* W1, const float* bi1, float* u1, float* w1,
    const float* W2, const float* bi2, float* u2, float* w2,
    const float* W3, const float* bi3, float* u3, float* w3){
  const float *W, *bi; float *u, *w;
  switch (blockIdx.x){
    case 0: W=W0; bi=bi0; u=u0; w=w0; break;
    case 1: W=W1; bi=bi1; u=u1; w=w1; break;
    case 2: W=W2; bi=bi2; u=u2; w=w2; break;
    default:W=W3; bi=bi3; u=u3; w=w3; break;
  }
  int j = threadIdx.x;
  float su = 0.f, sw = 0.f;
  for (int i = 0; i < H; ++i) {
    float wv = W[i*H + j];
    su += e[i]*wv;
    sw += be[i]*wv;
  }
  u[j] = su;
  w[j] = sw + bi[j];
}

// ---------- MFMA GEMM ----------
static __device__ __forceinline__ void stage_w(const float* __restrict__ W,
    unsigned short* __restrict__ WH, unsigned short* __restrict__ WL, int tid){
  #pragma unroll
  for (int it = 0; it < 16; ++it){
    int gid = it*256 + tid;
    int n  = gid & 127;          // output col -> WT row
    int kg = gid >> 7;           // 0..31, group of 4 consecutive k
    int k0 = kg*4;
    float w0 = W[(k0+0)*H + n];
    float w1 = W[(k0+1)*H + n];
    float w2 = W[(k0+2)*H + n];
    float w3 = W[(k0+3)*H + n];
    unsigned short h0=f2b(w0), h1=f2b(w1), h2=f2b(w2), h3=f2b(w3);
    s16x4 hv; hv[0]=(short)h0; hv[1]=(short)h1; hv[2]=(short)h2; hv[3]=(short)h3;
    s16x4 lv; lv[0]=(short)f2b(w0-b2f(h0)); lv[1]=(short)f2b(w1-b2f(h1));
              lv[2]=(short)f2b(w2-b2f(h2)); lv[3]=(short)f2b(w3-b2f(h3));
    int base = n*128 + (((kg>>1) ^ (n&15))<<3) + ((kg&1)<<2);
    *(s16x4*)(WH + base) = hv;
    *(s16x4*)(WL + base) = lv;
  }
}

template<bool USE_AL>
static __device__ __forceinline__ void mfma_pass(const s16x8 AH[2][4], const s16x8 AL[2][4],
    const unsigned short* __restrict__ WH, const unsigned short* __restrict__ WL,
    int l15, int l4, f32x4 acc[2][8]){
  #pragma unroll
  for (int g = 0; g < 2; ++g)
    #pragma unroll
    for (int t = 0; t < 8; ++t){ acc[g][t][0]=0.f; acc[g][t][1]=0.f; acc[g][t][2]=0.f; acc[g][t][3]=0.f; }
  #pragma unroll
  for (int s = 0; s < 4; ++s){
    #pragma unroll
    for (int t = 0; t < 8; ++t){
      int n = t*16 + l15;
      int off = n*128 + (((s*4 + l4) ^ l15)<<3);
      s16x8 BH = *(const s16x8*)(WH + off);
      s16x8 BL = *(const s16x8*)(WL + off);
      #pragma unroll
      for (int g = 0; g < 2; ++g){
        acc[g][t] = __builtin_amdgcn_mfma_f32_16x16x32_bf16(AH[g][s], BH, acc[g][t], 0,0,0);
        acc[g][t] = __builtin_amdgcn_mfma_f32_16x16x32_bf16(AH[g][s], BL, acc[g][t], 0,0,0);
        if constexpr (USE_AL)
          acc[g][t] = __builtin_amdgcn_mfma_f32_16x16x32_bf16(AL[g][s], BH, acc[g][t], 0,0,0);
      }
    }
  }
}

#define EPI_WRITE(ACC, BIAS)                                                    \
  {                                                                             \
    float bb[8];                                                                \
    _Pragma("unroll")                                                           \
    for (int t = 0; t < 8; ++t) bb[t] = BIAS[t*16 + l15];                       \
    _Pragma("unroll")                                                           \
    for (int g = 0; g < 2; ++g){                                                \
      _Pragma("unroll")                                                         \
      for (int t = 0; t < 8; ++t){                                              \
        _Pragma("unroll")                                                       \
        for (int r = 0; r < 4; ++r)                                             \
          EPI[w*32 + g*16 + l4*4 + r][t*16 + l15] = ACC[g][t][r] + bb[t];       \
      }                                                                         \
    }                                                                           \
  }

template<int BF>
static __device__ __forceinline__ void epi_store(void* Y, int ld, int of, int row0, int M,
                                                 int tid, const float (*EPI)[132]){
  #pragma unroll
  for (int it = 0; it < 16; ++it){
    int fid = it*256 + tid;
    int r = fid >> 5, c4 = (fid & 31) << 2;
    int grow = row0 + r;
    if (grow < M){
      float4 v = *(const float4*)&EPI[r][c4];
      if constexpr (BF){
        ushort4 hv; hv.x=f2b(v.x); hv.y=f2b(v.y); hv.z=f2b(v.z); hv.w=f2b(v.w);
        *(ushort4*)((unsigned short*)Y + (size_t)grow*ld + of + c4) = hv;
      } else {
        *(float4*)((float*)Y + (size_t)grow*ld + of + c4) = v;
      }
    }
  }
}

// XB: X input is bf16 (skip lo-term MFMAs). DOTS1: pass1 feeds rank-1 dots only.
template<int XB, int DOTS1, int B1, int B2, int TWO>
__launch_bounds__(256)
__global__ void mgemm(const void* __restrict__ Xv, int M,
    const float* __restrict__ W1, const float* __restrict__ b1,
    void* __restrict__ Y1, int ld1, int of1,
    const float* __restrict__ uvec, const float* __restrict__ wvec,
    float* __restrict__ aout, float* __restrict__ cout,
    const float* __restrict__ W2, const float* __restrict__ b2,
    void* __restrict__ Y2, int ld2, int of2){
  __shared__ __align__(16) char smem[128*132*4];
  unsigned short* WH = (unsigned short*)smem;
  unsigned short* WL = WH + 16384;
  float (*EPI)[132] = (float(*)[132])smem;

  int tid = threadIdx.x;
  int lane = tid & 63, w = tid >> 6;
  int l15 = lane & 15, l4 = lane >> 4;
  int row0 = blockIdx.x * 128;

  s16x8 AH[2][4], AL[2][4];
  if constexpr (XB){
    const unsigned short* Xb = (const unsigned short*)Xv;
    #pragma unroll
    for (int g = 0; g < 2; ++g){
      int row = row0 + w*32 + g*16 + l15;
      const unsigned short* xr = Xb + (size_t)row*H;
      bool ok = row < M;
      #pragma unroll
      for (int s = 0; s < 4; ++s){
        s16x8 h = {0,0,0,0,0,0,0,0};
        if (ok) h = *(const s16x8*)(xr + s*32 + l4*8);
        AH[g][s] = h;
      }
    }
  } else {
    const float* X = (const float*)Xv;
    #pragma unroll
    for (int g = 0; g < 2; ++g){
      int row = row0 + w*32 + g*16 + l15;
      const float* xr = X + (size_t)row*H;
      bool ok = row < M;
      #pragma unroll
      for (int s = 0; s < 4; ++s){
        int kb = s*32 + l4*8;
        float4 f0 = ok ? *(const float4*)(xr+kb)   : make_float4(0.f,0.f,0.f,0.f);
        float4 f1 = ok ? *(const float4*)(xr+kb+4) : make_float4(0.f,0.f,0.f,0.f);
        float xs[8] = {f0.x,f0.y,f0.z,f0.w,f1.x,f1.y,f1.z,f1.w};
        s16x8 h, lo;
        #pragma unroll
        for (int e = 0; e < 8; ++e){
          unsigned short hh = f2b(xs[e]);
          h[e]  = (short)hh;
          lo[e] = (short)f2b(xs[e] - b2f(hh));
        }
        AH[g][s] = h; AL[g][s] = lo;
      }
    }
  }

  stage_w(W1, WH, WL, tid);
  __syncthreads();

  f32x4 acc[2][8];
  mfma_pass<!XB>(AH, AL, WH, WL, l15, l4, acc);

  if constexpr (DOTS1){
    float ub[8], wb[8], bb[8];
    #pragma unroll
    for (int t = 0; t < 8; ++t){
      ub[t]=uvec[t*16+l15]; wb[t]=wvec[t*16+l15]; bb[t]=b1[t*16+l15];
    }
    #pragma unroll
    for (int g = 0; g < 2; ++g){
      #pragma unroll
      for (int r = 0; r < 4; ++r){
        float pa = 0.f, pc = 0.f;
        #pragma unroll
        for (int t = 0; t < 8; ++t){
          float y = acc[g][t][r] + bb[t];
          pa += y*ub[t]; pc += y*wb[t];
        }
        #pragma unroll
        for (int o = 1; o < 16; o <<= 1){ pa += __shfl_xor(pa,o); pc += __shfl_xor(pc,o); }
        int row = row0 + w*32 + g*16 + l4*4 + r;
        if (l15 == 0 && row < M){ aout[row] = pa; cout[row] = pc; }
      }
    }
  } else {
    __syncthreads();
    EPI_WRITE(acc, b1);
    __syncthreads();
    epi_store<B1>(Y1, ld1, of1, row0, M, tid, EPI);
  }

  if constexpr (TWO){
    __syncthreads();
    stage_w(W2, WH, WL, tid);
    __syncthreads();
    f32x4 acc2[2][8];
    mfma_pass<!XB>(AH, AL, WH, WL, l15, l4, acc2);
    __syncthreads();
    EPI_WRITE(acc2, b2);
    __syncthreads();
    epi_store<B2>(Y2, ld2, of2, row0, M, tid, EPI);
  }
}

// ---------- merged CSR build ----------
__global__ void kcount2(const int* __restrict__ dst_tp, const int* __restrict__ dst_pt,
                        int* __restrict__ degP, int* __restrict__ degT, int n){
  int i = blockIdx.x*256 + threadIdx.x;
  if (i < n){ atomicAdd(&degP[dst_tp[i]], 1); atomicAdd(&degT[dst_pt[i]], 1); }
}
__global__ void kscat2(const int* __restrict__ dst_tp, const int* __restrict__ src_tp,
                       const float* __restrict__ xv, int* __restrict__ curP,
                       float* __restrict__ valsP,
                       const int* __restrict__ dst_pt, const int* __restrict__ src_pt,
                       int* __restrict__ curT, int* __restrict__ srcsT, int n){
  int i = blockIdx.x*256 + threadIdx.x;
  if (i < n){
    int p1 = atomicAdd(&curP[dst_tp[i]], 1); valsP[p1] = xv[src_tp[i]];
    int p2 = atomicAdd(&curT[dst_pt[i]], 1); srcsT[p2] = src_pt[i];
  }
}
__global__ void kscan1(const int* __restrict__ in, int* __restrict__ out,
                       int* __restrict__ bsums, int n){
  __shared__ int sh[256];
  int t = threadIdx.x, i = blockIdx.x*256 + t;
  int v = (i<n)? in[i] : 0;
  sh[t] = v; __syncthreads();
  for (int off=1; off<256; off<<=1){
    int u = (t>=off)? sh[t-off] : 0;
    __syncthreads();
    sh[t] += u;
    __syncthreads();
  }
  if (i<n) out[i] = sh[t]-v;
  if (t==255) bsums[blockIdx.x] = sh[255];
}
__launch_bounds__(1024)
__global__ void kscan2(int* __restrict__ bsums, int n){
  __shared__ int sh[1024];
  int t = threadIdx.x;
  int v = (t<n)? bsums[t] : 0;
  sh[t] = v; __syncthreads();
  for (int off=1; off<1024; off<<=1){
    int u = (t>=off)? sh[t-off] : 0;
    __syncthreads();
    sh[t] += u;
    __syncthreads();
  }
  if (t<n) bsums[t] = sh[t]-v;
}
__global__ void kscanadd(int* __restrict__ out, const int* __restrict__ bsums, int n){
  int i = blockIdx.x*256 + threadIdx.x;
  if (i<n) out[i] += bsums[blockIdx.x];
}

// ---------- beta gate + combine; OB: bf16 output ----------
template<int OB>
static __device__ __forceinline__ void beta_combine(float4 o, float4 sk,
    const float* __restrict__ Wb, int lane, bool leaky, void* __restrict__ dstRow){
  float4 wb0 = *(const float4*)&Wb[lane*4];
  float4 wb1 = *(const float4*)&Wb[H   + lane*4];
  float4 wb2 = *(const float4*)&Wb[2*H + lane*4];
  float4 dv = make_float4(o.x-sk.x, o.y-sk.y, o.z-sk.z, o.w-sk.w);
  float part = dot4(o,wb0) + dot4(sk,wb1) + dot4(dv,wb2);
  #pragma unroll
  for (int off=1; off<32; off<<=1) part += __shfl_xor(part, off);
  float beta = 1.f/(1.f + __expf(-part));
  float4 r;
  r.x = beta*sk.x + (1.f-beta)*o.x;
  r.y = beta*sk.y + (1.f-beta)*o.y;
  r.z = beta*sk.z + (1.f-beta)*o.z;
  r.w = beta*sk.w + (1.f-beta)*o.w;
  if (leaky){
    r.x = r.x>0.f? r.x : 0.01f*r.x;
    r.y = r.y>0.f? r.y : 0.01f*r.y;
    r.z = r.z>0.f? r.z : 0.01f*r.z;
    r.w = r.w>0.f? r.w : 0.01f*r.w;
  }
  if constexpr (OB){
    ushort4 h; h.x=f2b(r.x); h.y=f2b(r.y); h.z=f2b(r.z); h.w=f2b(r.w);
    *(ushort4*)((unsigned short*)dstRow + lane*4) = h;
  } else {
    *(float4*)((float*)dstRow + lane*4) = r;
  }
}

// ---------- tconv1: scalar online softmax per phrase ----------
__global__ void knode1(const int* __restrict__ rowptr, const int* __restrict__ deg,
                       const float* __restrict__ vals,
                       const float* __restrict__ a1, const float* __restrict__ c1,
                       float* __restrict__ dden, float* __restrict__ dsv, int n){
  int p = blockIdx.x*256 + threadIdx.x;
  if (p >= n) return;
  float a = a1[p], c = c1[p];
  int rp = rowptr[p], dg = deg[p];
  const float RS = 0.08838834764831845f;
  float m = -INFINITY, d = 0.f, sv = 0.f;
  for (int i = 0; i < dg; ++i) {
    float x = __builtin_nontemporal_load(&vals[rp+i]);
    float s = (x*a + c)*RS;
    if (s > m){ float sc = __expf(m - s); d *= sc; sv *= sc; m = s; }
    float pp = __expf(s - m);
    d += pp; sv += pp*x;
  }
  dden[p] = d; dsv[p] = sv;
}

__global__ void kcomb1(const float* __restrict__ dden, const float* __restrict__ dsv,
                       const float* __restrict__ uv, const float* __restrict__ wv,
                       const unsigned short* __restrict__ S, const float* __restrict__ Wb,
                       unsigned short* __restrict__ out, int n){
  int gid = (blockIdx.x*blockDim.x + threadIdx.x) >> 5;
  int lane = threadIdx.x & 31;
  if (gid >= n) return;
  float d = dden[gid], sv = dsv[gid];
  float inv = 1.f/(d + 1e-16f);
  float4 u4 = *(const float4*)&uv[lane*4];
  float4 w4 = *(const float4*)&wv[lane*4];
  float4 o = make_float4((sv*u4.x + d*w4.x)*inv, (sv*u4.y + d*w4.y)*inv,
                         (sv*u4.z + d*w4.z)*inv, (sv*u4.w + d*w4.w)*inv);
  u16x4 sh4 = __builtin_nontemporal_load((const u16x4*)(S + (size_t)gid*H + lane*4));
  float4 sk = cvt4u(sh4);
  beta_combine<1>(o, sk, Wb, lane, true, out + (size_t)gid*H);
}

// ---------- tconv2: bf16 V gather, 1-deep prefetch ----------
__global__ void knode2(const float* __restrict__ x_tok, const float* __restrict__ ak,
                       const float* __restrict__ ck, const unsigned short* __restrict__ Vb,
                       const int* __restrict__ rowptr, const int* __restrict__ deg,
                       const int* __restrict__ srcs,
                       const float* __restrict__ us, const float* __restrict__ ws,
                       const float* __restrict__ Wb, unsigned short* __restrict__ out, int n){
  int gid = (blockIdx.x*blockDim.x + threadIdx.x) >> 5;
  int lane = threadIdx.x & 31;
  if (gid >= n) return;
  float xt = x_tok[gid];
  int rp = rowptr[gid], dg = deg[gid];
  const float RS = 0.08838834764831845f;
  float m = -INFINITY, d = 0.f;
  float4 acc = make_float4(0.f,0.f,0.f,0.f);
  int sp = 0; ushort4 hv = make_ushort4(0,0,0,0);
  if (dg > 0){
    sp = srcs[rp];
    hv = *(const ushort4*)(Vb + (size_t)sp*H + lane*4);
  }
  for (int i = 0; i < dg; ++i) {
    int spn = sp; ushort4 hvn = hv;
    if (i+1 < dg){
      spn = srcs[rp+i+1];
      hvn = *(const ushort4*)(Vb + (size_t)spn*H + lane*4);
    }
    float s = (xt*ak[sp] + ck[sp])*RS;
    float4 v = cvt4(hv);
    if (s > m){
      float sc = __expf(m - s);
      d *= sc; acc.x *= sc; acc.y *= sc; acc.z *= sc; acc.w *= sc;
      m = s;
    }
    float pp = __expf(s - m);
    d += pp;
    acc.x += pp*v.x; acc.y += pp*v.y; acc.z += pp*v.z; acc.w += pp*v.w;
    sp = spn; hv = hvn;
  }
  float inv = 1.f/(d + 1e-16f);
  float4 o = make_float4(acc.x*inv, acc.y*inv, acc.z*inv, acc.w*inv);
  float4 u4 = *(const float4*)&us[lane*4];
  float4 w4 = *(const float4*)&ws[lane*4];
  float4 sk = make_float4(xt*u4.x+w4.x, xt*u4.y+w4.y, xt*u4.z+w4.z, xt*u4.w+w4.w);
  beta_combine<1>(o, sk, Wb, lane, true, out + (size_t)gid*H);
}

// ---------- tconv3: bf16 Q/S streams (nt), bf16 KV gather, 1-deep prefetch ----------
__global__ void knode3(const unsigned short* __restrict__ Q, const unsigned short* __restrict__ KV,
                       const unsigned short* __restrict__ S,
                       const int* __restrict__ rowptr, const int* __restrict__ deg,
                       const int* __restrict__ srcs,
                       const float* __restrict__ Wb, unsigned short* __restrict__ out, int n){
  int gid = (blockIdx.x*blockDim.x + threadIdx.x) >> 5;
  int lane = threadIdx.x & 31;
  if (gid >= n) return;
  u16x4 qh = __builtin_nontemporal_load((const u16x4*)(Q + (size_t)gid*H + lane*4));
  float4 q = cvt4u(qh);
  int rp = rowptr[gid], dg = deg[gid];
  const float RS = 0.08838834764831845f;
  float m = -INFINITY, d = 0.f;
  float4 acc = make_float4(0.f,0.f,0.f,0.f);
  ushort4 hk = make_ushort4(0,0,0,0), hv = make_ushort4(0,0,0,0);
  if (dg > 0){
    int sp = srcs[rp];
    const ushort4* kvp = (const ushort4*)(KV + (size_t)sp*256);
    hk = kvp[lane]; hv = kvp[32 + lane];
  }
  for (int i = 0; i < dg; ++i) {
    ushort4 hkn = hk, hvn = hv;
    if (i+1 < dg){
      int spn = srcs[rp+i+1];
      const ushort4* kvn = (const ushort4*)(KV + (size_t)spn*256);
      hkn = kvn[lane]; hvn = kvn[32 + lane];
    }
    float4 kk = cvt4(hk);
    float ps = dot4(q, kk);
    #pragma unroll
    for (int off=1; off<32; off<<=1) ps += __shfl_xor(ps, off);
    float s = ps*RS;
    float4 v = cvt4(hv);
    if (s > m){
      float sc = __expf(m - s);
      d *= sc; acc.x *= sc; acc.y *= sc; acc.z *= sc; acc.w *= sc;
      m = s;
    }
    float pp = __expf(s - m);
    d += pp;
    acc.x += pp*v.x; acc.y += pp*v.y; acc.z += pp*v.z; acc.w += pp*v.w;
    hk = hkn; hv = hvn;
  }
  float inv = 1.f/(d + 1e-16f);
  float4 o = make_float4(acc.x*inv, acc.y*inv, acc.z*inv, acc.w*inv);
  u16x4 sh4 = __builtin_nontemporal_load((const u16x4*)(S + (size_t)gid*H + lane*4));
  float4 sk = cvt4u(sh4);
  beta_combine<1>(o, sk, Wb, lane, false, out + (size_t)gid*H);
}

extern "C" void kernel_launch(void* const* d_in, const int* in_sizes, int n_in,
                              void* d_out, int out_size, void* d_ws, size_t ws_size,
                              hipStream_t stream){
  const float* x_token  = (const float*)d_in[0];
  const float* x_phrase = (const float*)d_in[1];
  const float* W_emb    = (const float*)d_in[2];
  const float* b_emb    = (const float*)d_in[3];
  const float* Wq_tp = (const float*)d_in[4];  const float* bq_tp = (const float*)d_in[5];
  const float* Wk_tp = (const float*)d_in[6];  const float* bk_tp = (const float*)d_in[7];
  const float* Wv_tp = (const float*)d_in[8];  const float* bv_tp = (const float*)d_in[9];
  const float* Ws_tp = (const float*)d_in[10]; const float* bs_tp = (const float*)d_in[11];
  const float* Wb_tp = (const float*)d_in[12];
  const float* Wq_pt = (const float*)d_in[13]; const float* bq_pt = (const float*)d_in[14];
  const float* Wk_pt = (const float*)d_in[15]; const float* bk_pt = (const float*)d_in[16];
  const float* Wv_pt = (const float*)d_in[17]; const float* bv_pt = (const float*)d_in[18];
  const float* Ws_pt = (const float*)d_in[19]; const float* bs_pt = (const float*)d_in[20];
  const float* Wb_pt = (const float*)d_in[21];
  const float* W_head = (const float*)d_in[22]; const float* b_head = (const float*)d_in[23];
  const int* src_tp = (const int*)d_in[24];
  const int* dst_tp = (const int*)d_in[25];
  const int* src_pt = (const int*)d_in[26];
  const int* dst_pt = (const int*)d_in[27];
  float* out = (float*)d_out;

  // ---- workspace carve ----
  char* base = (char*)d_ws;
  size_t off = 0;
  auto AF = [&](size_t n)->float*{ float* p=(float*)(base+off); off += ((n+3)&~(size_t)3)*4; return p; };
  auto AI = [&](size_t n)->int*  { int*   p=(int*)  (base+off); off += ((n+3)&~(size_t)3)*4; return p; };
  float* B  = AF((size_t)NP*H);   // s1 bf16; later KVb bf16 [NP][256]
  float* P1 = AF((size_t)NP*H);   // p1 bf16
  float* C  = AF((size_t)NT*H);   // Vb bf16 early; q3 bf16 later
  float* D  = AF((size_t)NT*H);   // s3 bf16
  float* T1 = AF((size_t)NT*H);   // t1 bf16, then t2 bf16
  unsigned short* S1b = (unsigned short*)B;
  unsigned short* KVb = (unsigned short*)B;
  unsigned short* P1b = (unsigned short*)P1;
  unsigned short* Vb  = (unsigned short*)C;
  unsigned short* Qb  = (unsigned short*)C;
  unsigned short* Sb  = (unsigned short*)D;
  unsigned short* T1b = (unsigned short*)T1;
  float* vecs = AF(8*H);
  float* uk1=vecs, *wk1=vecs+H, *uv1=vecs+2*H, *wv1=vecs+3*H;
  float* uq2=vecs+4*H, *wq2=vecs+5*H, *us2=vecs+6*H, *ws2=vecs+7*H;
  float* a1   = AF(NP); float* c1  = AF(NP);
  float* dden = AF(NP); float* dsv = AF(NP);
  int* deg = AI(NP+NT);  // degP | degT
  int* row = AI(NP+NT);  // rowP | rowT
  int* cur = AI(NP+NT);
  float* valsP = AF(NE);
  int*   srcsT = AI(NE);
  int* bsums = AI(1024);
  int* degP = deg,    * degT = deg + NP;
  int* rowP = row,    * rowT = row + NP;
  int* curP = cur,    * curT = cur + NP;
  (void)ws_size; (void)in_sizes; (void)n_in; (void)out_size;

  const int nbP = CDIV(NP,256), nbT = CDIV(NT,256), nbE = CDIV(NE,256);
  const int gP = CDIV(NP,128), gT = CDIV(NT,128);

  kvec4<<<4,H,0,stream>>>(W_emb, b_emb,
      Wk_tp, bk_tp, uk1, wk1,
      Wv_tp, bv_tp, uv1, wv1,
      Wq_pt, bq_pt, uq2, wq2,
      Ws_pt, bs_pt, us2, ws2);

  // merged CSR build for both graphs
  (void)hipMemsetAsync(deg, 0, (size_t)(NP+NT)*4, stream);
  kcount2<<<nbE,256,0,stream>>>(dst_tp, dst_pt, degP, degT, NE);
  kscan1<<<nbP,256,0,stream>>>(degP, rowP, bsums, NP);
  kscan2<<<1,1024,0,stream>>>(bsums, nbP);
  kscanadd<<<nbP,256,0,stream>>>(rowP, bsums, NP);
  kscan1<<<nbT,256,0,stream>>>(degT, rowT, bsums, NT);
  kscan2<<<1,1024,0,stream>>>(bsums, nbT);
  kscanadd<<<nbT,256,0,stream>>>(rowT, bsums, NT);
  (void)hipMemcpyAsync(cur, row, (size_t)(NP+NT)*4, hipMemcpyDeviceToDevice, stream);
  kscat2<<<nbE,256,0,stream>>>(dst_tp, src_tp, x_token, curP, valsP,
                               dst_pt, src_pt, curT, srcsT, NE);

  // tconv1: pass1 = q1 (fused dots), pass2 = s1 -> bf16
  mgemm<0,1,0,1,1><<<gP,256,0,stream>>>(x_phrase, NP,
      Wq_tp, bq_tp, nullptr, 0, 0, uk1, wk1, a1, c1,
      Ws_tp, bs_tp, S1b, H, 0);
  knode1<<<nbP,256,0,stream>>>(rowP, degP, valsP, a1, c1, dden, dsv, NP);
  kcomb1<<<CDIV(NP*32,256),256,0,stream>>>(dden, dsv, uv1, wv1, S1b, Wb_tp, P1b, NP);

  // tconv2: pass1 = k2 (fused dots vs rank-1 q2), pass2 = v2 -> bf16 Vb
  mgemm<0,1,0,1,1><<<gP,256,0,stream>>>(x_phrase, NP,
      Wk_pt, bk_pt, nullptr, 0, 0, uq2, wq2, a1, c1,
      Wv_pt, bv_pt, Vb, H, 0);
  knode2<<<CDIV(NT*32,256),256,0,stream>>>(x_token, a1, c1, Vb, rowT, degT, srcsT,
                                           us2, ws2, Wb_pt, T1b, NT);

  // tconv3: q3,s3 from bf16 t1 -> bf16; k3,v3 from bf16 p1 -> interleaved bf16 KV
  mgemm<1,0,1,1,1><<<gT,256,0,stream>>>(T1b, NT,
      Wq_pt, bq_pt, Qb, H, 0, nullptr, nullptr, nullptr, nullptr,
      Ws_pt, bs_pt, Sb, H, 0);
  mgemm<1,0,1,1,1><<<gP,256,0,stream>>>(P1b, NP,
      Wk_pt, bk_pt, KVb, 256, 0, nullptr, nullptr, nullptr, nullptr,
      Wv_pt, bv_pt, KVb, 256, H);
  knode3<<<CDIV(NT*32,256),256,0,stream>>>(Qb, KVb, Sb, rowT, degT, srcsT,
                                           Wb_pt, T1b, NT);

  // head: bf16 t2 -> fp32 out
  mgemm<1,0,0,0,0><<<gT,256,0,stream>>>(T1b, NT,
      W_head, b_head, out, H, 0, nullptr, nullptr, nullptr, nullptr,
      nullptr, nullptr, nullptr, 0, 0);
}

// Round 6
// 443.907 us; speedup vs baseline: 2.2568x; 1.1142x over previous
//
#include <hip/hip_runtime.h>
#include <math.h>

#define NT 100000
#define NP 50000
#define NE 800000
#define H 128

#define CDIV(a,b) (((a)+(b)-1)/(b))

typedef __attribute__((ext_vector_type(8))) short s16x8;
typedef __attribute__((ext_vector_type(4))) short s16x4;
typedef __attribute__((ext_vector_type(4))) unsigned short u16x4;
typedef __attribute__((ext_vector_type(4))) float f32x4;

static __device__ __forceinline__ float dot4(float4 a, float4 b){
  return a.x*b.x + a.y*b.y + a.z*b.z + a.w*b.w;
}
static __device__ __forceinline__ float b2f(unsigned short u){
  union { unsigned int i; float f; } c; c.i = ((unsigned int)u) << 16; return c.f;
}
static __device__ __forceinline__ unsigned short f2b(float f){
  union { float f; unsigned int i; } c; c.f = f;
  unsigned int x = c.i;
  unsigned int r = (x + 0x7fffu + ((x >> 16) & 1u)) >> 16;   // RNE
  return (unsigned short)r;
}
static __device__ __forceinline__ float4 cvt4(ushort4 h){
  return make_float4(b2f(h.x), b2f(h.y), b2f(h.z), b2f(h.w));
}
static __device__ __forceinline__ float4 cvt4u(u16x4 h){
  return make_float4(b2f(h[0]), b2f(h[1]), b2f(h[2]), b2f(h[3]));
}

// ---------- rank-1 helper vectors ----------
__global__ void kvec4(const float* __restrict__ e, const float* __restrict__ be,
    const float* W0, const float* bi0, float* u0, float* w0,
    const float* W1, const float* bi1, float* u1, float* w1,
    const float* W2, const float* bi2, float* u2, float* w2,
    const float* W3, const float* bi3, float* u3, float* w3){
  const float *W, *bi; float *u, *w;
  switch (blockIdx.x){
    case 0: W=W0; bi=bi0; u=u0; w=w0; break;
    case 1: W=W1; bi=bi1; u=u1; w=w1; break;
    case 2: W=W2; bi=bi2; u=u2; w=w2; break;
    default:W=W3; bi=bi3; u=u3; w=w3; break;
  }
  int j = threadIdx.x;
  float su = 0.f, sw = 0.f;
  for (int i = 0; i < H; ++i) {
    float wv = W[i*H + j];
    su += e[i]*wv;
    sw += be[i]*wv;
  }
  u[j] = su;
  w[j] = sw + bi[j];
}

// ---------- MFMA GEMM pieces ----------
static __device__ __forceinline__ void stage_w(const float* __restrict__ W,
    unsigned short* __restrict__ WH, unsigned short* __restrict__ WL, int tid){
  #pragma unroll
  for (int it = 0; it < 16; ++it){
    int gid = it*256 + tid;
    int n  = gid & 127;          // output col -> WT row
    int kg = gid >> 7;           // 0..31, group of 4 consecutive k
    int k0 = kg*4;
    float w0 = W[(k0+0)*H + n];
    float w1 = W[(k0+1)*H + n];
    float w2 = W[(k0+2)*H + n];
    float w3 = W[(k0+3)*H + n];
    unsigned short h0=f2b(w0), h1=f2b(w1), h2=f2b(w2), h3=f2b(w3);
    s16x4 hv; hv[0]=(short)h0; hv[1]=(short)h1; hv[2]=(short)h2; hv[3]=(short)h3;
    s16x4 lv; lv[0]=(short)f2b(w0-b2f(h0)); lv[1]=(short)f2b(w1-b2f(h1));
              lv[2]=(short)f2b(w2-b2f(h2)); lv[3]=(short)f2b(w3-b2f(h3));
    int base = n*128 + (((kg>>1) ^ (n&15))<<3) + ((kg&1)<<2);
    *(s16x4*)(WH + base) = hv;
    *(s16x4*)(WL + base) = lv;
  }
}

template<bool USE_AL>
static __device__ __forceinline__ void mfma_pass(const s16x8 AH[2][4], const s16x8 AL[2][4],
    const unsigned short* __restrict__ WH, const unsigned short* __restrict__ WL,
    int l15, int l4, f32x4 acc[2][8]){
  #pragma unroll
  for (int g = 0; g < 2; ++g)
    #pragma unroll
    for (int t = 0; t < 8; ++t){ acc[g][t][0]=0.f; acc[g][t][1]=0.f; acc[g][t][2]=0.f; acc[g][t][3]=0.f; }
  #pragma unroll
  for (int s = 0; s < 4; ++s){
    #pragma unroll
    for (int t = 0; t < 8; ++t){
      int n = t*16 + l15;
      int off = n*128 + (((s*4 + l4) ^ l15)<<3);
      s16x8 BH = *(const s16x8*)(WH + off);
      s16x8 BL = *(const s16x8*)(WL + off);
      #pragma unroll
      for (int g = 0; g < 2; ++g){
        acc[g][t] = __builtin_amdgcn_mfma_f32_16x16x32_bf16(AH[g][s], BH, acc[g][t], 0,0,0);
        acc[g][t] = __builtin_amdgcn_mfma_f32_16x16x32_bf16(AH[g][s], BL, acc[g][t], 0,0,0);
        if constexpr (USE_AL)
          acc[g][t] = __builtin_amdgcn_mfma_f32_16x16x32_bf16(AL[g][s], BH, acc[g][t], 0,0,0);
      }
    }
  }
}

#define EPI_WRITE(ACC, BIAS)                                                    \
  {                                                                             \
    float bb[8];                                                                \
    _Pragma("unroll")                                                           \
    for (int t = 0; t < 8; ++t) bb[t] = BIAS[t*16 + l15];                       \
    _Pragma("unroll")                                                           \
    for (int g = 0; g < 2; ++g){                                                \
      _Pragma("unroll")                                                         \
      for (int t = 0; t < 8; ++t){                                              \
        _Pragma("unroll")                                                       \
        for (int r = 0; r < 4; ++r)                                             \
          EPI[w*32 + g*16 + l4*4 + r][t*16 + l15] = ACC[g][t][r] + bb[t];       \
      }                                                                         \
    }                                                                           \
  }

template<int BF>
static __device__ __forceinline__ void epi_store(void* Y, int ld, int of, int row0, int M,
                                                 int tid, const float (*EPI)[132]){
  #pragma unroll
  for (int it = 0; it < 16; ++it){
    int fid = it*256 + tid;
    int r = fid >> 5, c4 = (fid & 31) << 2;
    int grow = row0 + r;
    if (grow < M){
      float4 v = *(const float4*)&EPI[r][c4];
      if constexpr (BF){
        ushort4 hv; hv.x=f2b(v.x); hv.y=f2b(v.y); hv.z=f2b(v.z); hv.w=f2b(v.w);
        *(ushort4*)((unsigned short*)Y + (size_t)grow*ld + of + c4) = hv;
      } else {
        *(float4*)((float*)Y + (size_t)grow*ld + of + c4) = v;
      }
    }
  }
}

static __device__ __forceinline__ void dots_epi(const f32x4 (&acc)[2][8],
    const float* __restrict__ bias, const float* __restrict__ uvec,
    const float* __restrict__ wvec, float2* __restrict__ acout,
    int row0, int M, int w, int l15, int l4){
  float ub[8], wb[8], bb[8];
  #pragma unroll
  for (int t=0;t<8;++t){ ub[t]=uvec[t*16+l15]; wb[t]=wvec[t*16+l15]; bb[t]=bias[t*16+l15]; }
  #pragma unroll
  for (int g=0; g<2; ++g){
    #pragma unroll
    for (int r=0;r<4;++r){
      float pa=0.f, pc=0.f;
      #pragma unroll
      for (int t=0;t<8;++t){ float y=acc[g][t][r]+bb[t]; pa+=y*ub[t]; pc+=y*wb[t]; }
      #pragma unroll
      for (int o=1;o<16;o<<=1){ pa+=__shfl_xor(pa,o); pc+=__shfl_xor(pc,o); }
      int row=row0+w*32+g*16+l4*4+r;
      if (l15==0 && row<M) acout[row]=make_float2(pa,pc);
    }
  }
}

// A-fragment loaders
static __device__ __forceinline__ void load_a_f32(const float* __restrict__ X, int M,
    int row0, int w, int l15, int l4, s16x8 AH[2][4], s16x8 AL[2][4]){
  #pragma unroll
  for (int g = 0; g < 2; ++g){
    int row = row0 + w*32 + g*16 + l15;
    const float* xr = X + (size_t)row*H;
    bool ok = row < M;
    #pragma unroll
    for (int s = 0; s < 4; ++s){
      int kb = s*32 + l4*8;
      float4 f0 = ok ? *(const float4*)(xr+kb)   : make_float4(0.f,0.f,0.f,0.f);
      float4 f1 = ok ? *(const float4*)(xr+kb+4) : make_float4(0.f,0.f,0.f,0.f);
      float xs[8] = {f0.x,f0.y,f0.z,f0.w,f1.x,f1.y,f1.z,f1.w};
      s16x8 h, lo;
      #pragma unroll
      for (int e = 0; e < 8; ++e){
        unsigned short hh = f2b(xs[e]);
        h[e]  = (short)hh;
        lo[e] = (short)f2b(xs[e] - b2f(hh));
      }
      AH[g][s] = h; AL[g][s] = lo;
    }
  }
}
static __device__ __forceinline__ void load_a_bf16(const unsigned short* __restrict__ Xb, int M,
    int row0, int w, int l15, int l4, s16x8 AH[2][4]){
  #pragma unroll
  for (int g = 0; g < 2; ++g){
    int row = row0 + w*32 + g*16 + l15;
    const unsigned short* xr = Xb + (size_t)row*H;
    bool ok = row < M;
    #pragma unroll
    for (int s = 0; s < 4; ++s){
      s16x8 h = {0,0,0,0,0,0,0,0};
      if (ok) h = *(const s16x8*)(xr + s*32 + l4*8);
      AH[g][s] = h;
    }
  }
}

// ---------- fused phrase-side GEMM: 4 passes sharing X fragments ----------
__launch_bounds__(256)
__global__ void mgemm_ph(const float* __restrict__ X, int M,
    const float* __restrict__ Wq, const float* __restrict__ bq,
    const float* __restrict__ uk, const float* __restrict__ wk, float2* __restrict__ ac1,
    const float* __restrict__ Ws, const float* __restrict__ bs, unsigned short* __restrict__ S1b,
    const float* __restrict__ Wk, const float* __restrict__ bk,
    const float* __restrict__ uq, const float* __restrict__ wq, float2* __restrict__ ac2,
    const float* __restrict__ Wv, const float* __restrict__ bv, unsigned short* __restrict__ Vb){
  __shared__ __align__(16) char smem[128*132*4];
  unsigned short* WH = (unsigned short*)smem;
  unsigned short* WL = WH + 16384;
  float (*EPI)[132] = (float(*)[132])smem;
  int tid=threadIdx.x, lane=tid&63, w=tid>>6, l15=lane&15, l4=lane>>4;
  int row0 = blockIdx.x*128;

  s16x8 AH[2][4], AL[2][4];
  load_a_f32(X, M, row0, w, l15, l4, AH, AL);

  f32x4 acc[2][8];
  // pass1: q1 -> rank-1 dots (ac1)
  stage_w(Wq, WH, WL, tid); __syncthreads();
  mfma_pass<true>(AH, AL, WH, WL, l15, l4, acc);
  dots_epi(acc, bq, uk, wk, ac1, row0, M, w, l15, l4);
  __syncthreads();
  // pass2: s1 -> bf16
  stage_w(Ws, WH, WL, tid); __syncthreads();
  mfma_pass<true>(AH, AL, WH, WL, l15, l4, acc);
  __syncthreads(); EPI_WRITE(acc, bs); __syncthreads();
  epi_store<1>(S1b, H, 0, row0, M, tid, EPI);
  __syncthreads();
  // pass3: k2 -> rank-1 dots (ac2)
  stage_w(Wk, WH, WL, tid); __syncthreads();
  mfma_pass<true>(AH, AL, WH, WL, l15, l4, acc);
  dots_epi(acc, bk, uq, wq, ac2, row0, M, w, l15, l4);
  __syncthreads();
  // pass4: v2 -> bf16
  stage_w(Wv, WH, WL, tid); __syncthreads();
  mfma_pass<true>(AH, AL, WH, WL, l15, l4, acc);
  __syncthreads(); EPI_WRITE(acc, bv); __syncthreads();
  epi_store<1>(Vb, H, 0, row0, M, tid, EPI);
}

// ---------- generic 1/2-pass GEMM (bf16 or fp32 X) ----------
template<int XB, int B1, int B2, int TWO>
__launch_bounds__(256)
__global__ void mgemm(const void* __restrict__ Xv, int M,
    const float* __restrict__ W1, const float* __restrict__ b1,
    void* __restrict__ Y1, int ld1, int of1,
    const float* __restrict__ W2, const float* __restrict__ b2,
    void* __restrict__ Y2, int ld2, int of2){
  __shared__ __align__(16) char smem[128*132*4];
  unsigned short* WH = (unsigned short*)smem;
  unsigned short* WL = WH + 16384;
  float (*EPI)[132] = (float(*)[132])smem;
  int tid=threadIdx.x, lane=tid&63, w=tid>>6, l15=lane&15, l4=lane>>4;
  int row0 = blockIdx.x*128;

  s16x8 AH[2][4], AL[2][4];
  if constexpr (XB) load_a_bf16((const unsigned short*)Xv, M, row0, w, l15, l4, AH);
  else              load_a_f32((const float*)Xv, M, row0, w, l15, l4, AH, AL);

  stage_w(W1, WH, WL, tid); __syncthreads();
  f32x4 acc[2][8];
  mfma_pass<!XB>(AH, AL, WH, WL, l15, l4, acc);
  __syncthreads();
  EPI_WRITE(acc, b1);
  __syncthreads();
  epi_store<B1>(Y1, ld1, of1, row0, M, tid, EPI);

  if constexpr (TWO){
    __syncthreads();
    stage_w(W2, WH, WL, tid); __syncthreads();
    f32x4 acc2[2][8];
    mfma_pass<!XB>(AH, AL, WH, WL, l15, l4, acc2);
    __syncthreads();
    EPI_WRITE(acc2, b2);
    __syncthreads();
    epi_store<B2>(Y2, ld2, of2, row0, M, tid, EPI);
  }
}

// ---------- token-side CSR build (4 edges/thread MLP) ----------
__global__ void kcountT(const int* __restrict__ dst, int* __restrict__ deg, int n){
  int i0 = (blockIdx.x*256 + threadIdx.x)*4;
  if (i0 >= n) return;
  int4 d4 = *(const int4*)&dst[i0];
  atomicAdd(&deg[d4.x], 1);
  atomicAdd(&deg[d4.y], 1);
  atomicAdd(&deg[d4.z], 1);
  atomicAdd(&deg[d4.w], 1);
}
__global__ void kscatT(const int* __restrict__ dst, const int* __restrict__ src,
                       int* __restrict__ cur, int* __restrict__ srcs, int n){
  int i0 = (blockIdx.x*256 + threadIdx.x)*4;
  if (i0 >= n) return;
  int4 d4 = *(const int4*)&dst[i0];
  int4 s4 = *(const int4*)&src[i0];
  int p0 = atomicAdd(&cur[d4.x], 1);
  int p1 = atomicAdd(&cur[d4.y], 1);
  int p2 = atomicAdd(&cur[d4.z], 1);
  int p3 = atomicAdd(&cur[d4.w], 1);
  srcs[p0] = s4.x; srcs[p1] = s4.y; srcs[p2] = s4.z; srcs[p3] = s4.w;
}
__global__ void kscan1(const int* __restrict__ in, int* __restrict__ out,
                       int* __restrict__ bsums, int n){
  __shared__ int sh[256];
  int t = threadIdx.x, i = blockIdx.x*256 + t;
  int v = (i<n)? in[i] : 0;
  sh[t] = v; __syncthreads();
  for (int off=1; off<256; off<<=1){
    int u = (t>=off)? sh[t-off] : 0;
    __syncthreads();
    sh[t] += u;
    __syncthreads();
  }
  if (i<n) out[i] = sh[t]-v;
  if (t==255) bsums[blockIdx.x] = sh[255];
}
__launch_bounds__(1024)
__global__ void kscan2(int* __restrict__ bsums, int n){
  __shared__ int sh[1024];
  int t = threadIdx.x;
  int v = (t<n)? bsums[t] : 0;
  sh[t] = v; __syncthreads();
  for (int off=1; off<1024; off<<=1){
    int u = (t>=off)? sh[t-off] : 0;
    __syncthreads();
    sh[t] += u;
    __syncthreads();
  }
  if (t<n) bsums[t] = sh[t]-v;
}
__global__ void kscanadd(int* __restrict__ out, const int* __restrict__ bsums, int n){
  int i = blockIdx.x*256 + threadIdx.x;
  if (i<n) out[i] += bsums[blockIdx.x];
}

// ---------- tconv1: edge-parallel (no-max softmax), scalar atomics ----------
__global__ void knode1e(const int* __restrict__ src, const int* __restrict__ dst,
                        const float* __restrict__ xv, const float2* __restrict__ ac,
                        float2* __restrict__ dsv, int n){
  int i0 = (blockIdx.x*256 + threadIdx.x)*4;
  if (i0 >= n) return;
  const float RS = 0.08838834764831845f;
  int4 s4 = *(const int4*)&src[i0];
  int4 d4 = *(const int4*)&dst[i0];
  float x0 = xv[s4.x], x1 = xv[s4.y], x2 = xv[s4.z], x3 = xv[s4.w];
  float2 a0 = ac[d4.x], a1 = ac[d4.y], a2 = ac[d4.z], a3 = ac[d4.w];
  float e0 = __expf((x0*a0.x + a0.y)*RS);
  float e1 = __expf((x1*a1.x + a1.y)*RS);
  float e2 = __expf((x2*a2.x + a2.y)*RS);
  float e3 = __expf((x3*a3.x + a3.y)*RS);
  atomicAdd(&dsv[d4.x].x, e0); atomicAdd(&dsv[d4.x].y, e0*x0);
  atomicAdd(&dsv[d4.y].x, e1); atomicAdd(&dsv[d4.y].y, e1*x1);
  atomicAdd(&dsv[d4.z].x, e2); atomicAdd(&dsv[d4.z].y, e2*x2);
  atomicAdd(&dsv[d4.w].x, e3); atomicAdd(&dsv[d4.w].y, e3*x3);
}

// ---------- beta gate + combine; OB: bf16 output ----------
template<int OB>
static __device__ __forceinline__ void beta_combine(float4 o, float4 sk,
    const float* __restrict__ Wb, int lane, bool leaky, void* __restrict__ dstRow){
  float4 wb0 = *(const float4*)&Wb[lane*4];
  float4 wb1 = *(const float4*)&Wb[H   + lane*4];
  float4 wb2 = *(const float4*)&Wb[2*H + lane*4];
  float4 dv = make_float4(o.x-sk.x, o.y-sk.y, o.z-sk.z, o.w-sk.w);
  float part = dot4(o,wb0) + dot4(sk,wb1) + dot4(dv,wb2);
  #pragma unroll
  for (int off=1; off<32; off<<=1) part += __shfl_xor(part, off);
  float beta = 1.f/(1.f + __expf(-part));
  float4 r;
  r.x = beta*sk.x + (1.f-beta)*o.x;
  r.y = beta*sk.y + (1.f-beta)*o.y;
  r.z = beta*sk.z + (1.f-beta)*o.z;
  r.w = beta*sk.w + (1.f-beta)*o.w;
  if (leaky){
    r.x = r.x>0.f? r.x : 0.01f*r.x;
    r.y = r.y>0.f? r.y : 0.01f*r.y;
    r.z = r.z>0.f? r.z : 0.01f*r.z;
    r.w = r.w>0.f? r.w : 0.01f*r.w;
  }
  if constexpr (OB){
    ushort4 h; h.x=f2b(r.x); h.y=f2b(r.y); h.z=f2b(r.z); h.w=f2b(r.w);
    *(ushort4*)((unsigned short*)dstRow + lane*4) = h;
  } else {
    *(float4*)((float*)dstRow + lane*4) = r;
  }
}

__global__ void kcomb1(const float2* __restrict__ dsv,
                       const float* __restrict__ uv, const float* __restrict__ wv,
                       const unsigned short* __restrict__ S, const float* __restrict__ Wb,
                       unsigned short* __restrict__ out, int n){
  int gid = (blockIdx.x*blockDim.x + threadIdx.x) >> 5;
  int lane = threadIdx.x & 31;
  if (gid >= n) return;
  float2 ds = dsv[gid];
  float d = ds.x, sv = ds.y;
  float inv = 1.f/(d + 1e-16f);
  float4 u4 = *(const float4*)&uv[lane*4];
  float4 w4 = *(const float4*)&wv[lane*4];
  float4 o = make_float4((sv*u4.x + d*w4.x)*inv, (sv*u4.y + d*w4.y)*inv,
                         (sv*u4.z + d*w4.z)*inv, (sv*u4.w + d*w4.w)*inv);
  u16x4 sh4 = __builtin_nontemporal_load((const u16x4*)(S + (size_t)gid*H + lane*4));
  float4 sk = cvt4u(sh4);
  beta_combine<1>(o, sk, Wb, lane, true, out + (size_t)gid*H);
}

// ---------- tconv2: no-max, 2-way unrolled bf16 V gather ----------
__global__ void knode2(const float* __restrict__ x_tok, const float2* __restrict__ ac,
                       const unsigned short* __restrict__ Vb,
                       const int* __restrict__ rowptr, const int* __restrict__ deg,
                       const int* __restrict__ srcs,
                       const float* __restrict__ us, const float* __restrict__ ws,
                       const float* __restrict__ Wb, unsigned short* __restrict__ out, int n){
  int gid = (blockIdx.x*blockDim.x + threadIdx.x) >> 5;
  int lane = threadIdx.x & 31;
  if (gid >= n) return;
  float xt = x_tok[gid];
  int rp = rowptr[gid], dg = deg[gid];
  const float RS = 0.08838834764831845f;
  float d = 0.f;
  float4 acc = make_float4(0.f,0.f,0.f,0.f);
  int i = 0;
  for (; i+2 <= dg; i += 2){
    int spA = srcs[rp+i], spB = srcs[rp+i+1];
    ushort4 hA = *(const ushort4*)(Vb + (size_t)spA*H + lane*4);
    ushort4 hB = *(const ushort4*)(Vb + (size_t)spB*H + lane*4);
    float2 aA = ac[spA], aB = ac[spB];
    float eA = __expf((xt*aA.x + aA.y)*RS);
    float eB = __expf((xt*aB.x + aB.y)*RS);
    float4 vA = cvt4(hA), vB = cvt4(hB);
    d += eA + eB;
    acc.x += eA*vA.x + eB*vB.x;
    acc.y += eA*vA.y + eB*vB.y;
    acc.z += eA*vA.z + eB*vB.z;
    acc.w += eA*vA.w + eB*vB.w;
  }
  if (i < dg){
    int sp = srcs[rp+i];
    ushort4 hv = *(const ushort4*)(Vb + (size_t)sp*H + lane*4);
    float2 a = ac[sp];
    float e = __expf((xt*a.x + a.y)*RS);
    float4 v = cvt4(hv);
    d += e;
    acc.x += e*v.x; acc.y += e*v.y; acc.z += e*v.z; acc.w += e*v.w;
  }
  float inv = 1.f/(d + 1e-16f);
  float4 o = make_float4(acc.x*inv, acc.y*inv, acc.z*inv, acc.w*inv);
  float4 u4 = *(const float4*)&us[lane*4];
  float4 w4 = *(const float4*)&ws[lane*4];
  float4 sk = make_float4(xt*u4.x+w4.x, xt*u4.y+w4.y, xt*u4.z+w4.z, xt*u4.w+w4.w);
  beta_combine<1>(o, sk, Wb, lane, true, out + (size_t)gid*H);
}

// ---------- tconv3: no-max, 2-way unrolled bf16 KV gather ----------
__global__ void knode3(const unsigned short* __restrict__ Q, const unsigned short* __restrict__ KV,
                       const unsigned short* __restrict__ S,
                       const int* __restrict__ rowptr, const int* __restrict__ deg,
                       const int* __restrict__ srcs,
                       const float* __restrict__ Wb, unsigned short* __restrict__ out, int n){
  int gid = (blockIdx.x*blockDim.x + threadIdx.x) >> 5;
  int lane = threadIdx.x & 31;
  if (gid >= n) return;
  u16x4 qh = __builtin_nontemporal_load((const u16x4*)(Q + (size_t)gid*H + lane*4));
  float4 q = cvt4u(qh);
  int rp = rowptr[gid], dg = deg[gid];
  const float RS = 0.08838834764831845f;
  float d = 0.f;
  float4 acc = make_float4(0.f,0.f,0.f,0.f);
  int i = 0;
  for (; i+2 <= dg; i += 2){
    int spA = srcs[rp+i], spB = srcs[rp+i+1];
    const ushort4* kvA = (const ushort4*)(KV + (size_t)spA*256);
    const ushort4* kvB = (const ushort4*)(KV + (size_t)spB*256);
    ushort4 hkA = kvA[lane], hvA = kvA[32+lane];
    ushort4 hkB = kvB[lane], hvB = kvB[32+lane];
    float psA = dot4(q, cvt4(hkA));
    float psB = dot4(q, cvt4(hkB));
    #pragma unroll
    for (int off=1; off<32; off<<=1){ psA += __shfl_xor(psA,off); psB += __shfl_xor(psB,off); }
    float eA = __expf(psA*RS), eB = __expf(psB*RS);
    float4 vA = cvt4(hvA), vB = cvt4(hvB);
    d += eA + eB;
    acc.x += eA*vA.x + eB*vB.x;
    acc.y += eA*vA.y + eB*vB.y;
    acc.z += eA*vA.z + eB*vB.z;
    acc.w += eA*vA.w + eB*vB.w;
  }
  if (i < dg){
    int sp = srcs[rp+i];
    const ushort4* kvp = (const ushort4*)(KV + (size_t)sp*256);
    ushort4 hk = kvp[lane], hv = kvp[32+lane];
    float ps = dot4(q, cvt4(hk));
    #pragma unroll
    for (int off=1; off<32; off<<=1) ps += __shfl_xor(ps,off);
    float e = __expf(ps*RS);
    float4 v = cvt4(hv);
    d += e;
    acc.x += e*v.x; acc.y += e*v.y; acc.z += e*v.z; acc.w += e*v.w;
  }
  float inv = 1.f/(d + 1e-16f);
  float4 o = make_float4(acc.x*inv, acc.y*inv, acc.z*inv, acc.w*inv);
  u16x4 sh4 = __builtin_nontemporal_load((const u16x4*)(S + (size_t)gid*H + lane*4));
  float4 sk = cvt4u(sh4);
  beta_combine<1>(o, sk, Wb, lane, false, out + (size_t)gid*H);
}

extern "C" void kernel_launch(void* const* d_in, const int* in_sizes, int n_in,
                              void* d_out, int out_size, void* d_ws, size_t ws_size,
                              hipStream_t stream){
  const float* x_token  = (const float*)d_in[0];
  const float* x_phrase = (const float*)d_in[1];
  const float* W_emb    = (const float*)d_in[2];
  const float* b_emb    = (const float*)d_in[3];
  const float* Wq_tp = (const float*)d_in[4];  const float* bq_tp = (const float*)d_in[5];
  const float* Wk_tp = (const float*)d_in[6];  const float* bk_tp = (const float*)d_in[7];
  const float* Wv_tp = (const float*)d_in[8];  const float* bv_tp = (const float*)d_in[9];
  const float* Ws_tp = (const float*)d_in[10]; const float* bs_tp = (const float*)d_in[11];
  const float* Wb_tp = (const float*)d_in[12];
  const float* Wq_pt = (const float*)d_in[13]; const float* bq_pt = (const float*)d_in[14];
  const float* Wk_pt = (const float*)d_in[15]; const float* bk_pt = (const float*)d_in[16];
  const float* Wv_pt = (const float*)d_in[17]; const float* bv_pt = (const float*)d_in[18];
  const float* Ws_pt = (const float*)d_in[19]; const float* bs_pt = (const float*)d_in[20];
  const float* Wb_pt = (const float*)d_in[21];
  const float* W_head = (const float*)d_in[22]; const float* b_head = (const float*)d_in[23];
  const int* src_tp = (const int*)d_in[24];
  const int* dst_tp = (const int*)d_in[25];
  const int* src_pt = (const int*)d_in[26];
  const int* dst_pt = (const int*)d_in[27];
  float* out = (float*)d_out;

  // ---- workspace carve ----
  char* base = (char*)d_ws;
  size_t off = 0;
  auto AF = [&](size_t n)->float*{ float* p=(float*)(base+off); off += ((n+3)&~(size_t)3)*4; return p; };
  auto AI = [&](size_t n)->int*  { int*   p=(int*)  (base+off); off += ((n+3)&~(size_t)3)*4; return p; };
  float* B  = AF((size_t)NP*H);   // s1 bf16; later KVb bf16 [NP][256]
  float* P1 = AF((size_t)NP*H);   // p1 bf16
  float* C  = AF((size_t)NT*H);   // Vb bf16 early; Qb bf16 later
  float* D  = AF((size_t)NT*H);   // Sb bf16
  float* T1 = AF((size_t)NT*H);   // t1 bf16, then t2 bf16
  unsigned short* S1b = (unsigned short*)B;
  unsigned short* KVb = (unsigned short*)B;
  unsigned short* P1b = (unsigned short*)P1;
  unsigned short* Vb  = (unsigned short*)C;
  unsigned short* Qb  = (unsigned short*)C;
  unsigned short* Sb  = (unsigned short*)D;
  unsigned short* T1b = (unsigned short*)T1;
  float* vecs = AF(8*H);
  float* uk1=vecs, *wk1=vecs+H, *uv1=vecs+2*H, *wv1=vecs+3*H;
  float* uq2=vecs+4*H, *wq2=vecs+5*H, *us2=vecs+6*H, *ws2=vecs+7*H;
  float2* ac1  = (float2*)AF((size_t)2*NP);
  float2* ac2  = (float2*)AF((size_t)2*NP);
  float2* dsv2 = (float2*)AF((size_t)2*NP);
  int* degT = AI(NT); int* rowT = AI(NT); int* curT = AI(NT);
  int* srcsT = AI(NE);
  int* bsums = AI(1024);
  (void)ws_size; (void)in_sizes; (void)n_in; (void)out_size;

  const int nbT = CDIV(NT,256), nbE4 = CDIV(NE,1024);
  const int gP = CDIV(NP,128), gT = CDIV(NT,128);

  kvec4<<<4,H,0,stream>>>(W_emb, b_emb,
      Wk_tp, bk_tp, uk1, wk1,
      Wv_tp, bv_tp, uv1, wv1,
      Wq_pt, bq_pt, uq2, wq2,
      Ws_pt, bs_pt, us2, ws2);

  // token-side CSR + zero the phrase accumulators
  (void)hipMemsetAsync(degT, 0, (size_t)NT*4, stream);
  (void)hipMemsetAsync(dsv2, 0, (size_t)NP*8, stream);
  kcountT<<<nbE4,256,0,stream>>>(dst_pt, degT, NE);
  kscan1<<<nbT,256,0,stream>>>(degT, rowT, bsums, NT);
  kscan2<<<1,1024,0,stream>>>(bsums, nbT);
  kscanadd<<<nbT,256,0,stream>>>(rowT, bsums, NT);
  (void)hipMemcpyAsync(curT, rowT, (size_t)NT*4, hipMemcpyDeviceToDevice, stream);
  kscatT<<<nbE4,256,0,stream>>>(dst_pt, src_pt, curT, srcsT, NE);

  // fused phrase-side GEMMs: q1-dots(ac1), s1->S1b, k2-dots(ac2), v2->Vb
  mgemm_ph<<<gP,256,0,stream>>>(x_phrase, NP,
      Wq_tp, bq_tp, uk1, wk1, ac1,
      Ws_tp, bs_tp, S1b,
      Wk_pt, bk_pt, uq2, wq2, ac2,
      Wv_pt, bv_pt, Vb);

  // tconv1: edge-parallel accumulation + combine -> p1 (bf16)
  knode1e<<<nbE4,256,0,stream>>>(src_tp, dst_tp, x_token, ac1, dsv2, NE);
  kcomb1<<<CDIV(NP*32,256),256,0,stream>>>(dsv2, uv1, wv1, S1b, Wb_tp, P1b, NP);

  // tconv2 -> t1 (bf16)
  knode2<<<CDIV(NT*32,256),256,0,stream>>>(x_token, ac2, Vb, rowT, degT, srcsT,
                                           us2, ws2, Wb_pt, T1b, NT);

  // tconv3: q3,s3 from t1; k3,v3 from p1 -> interleaved KV
  mgemm<1,1,1,1><<<gT,256,0,stream>>>(T1b, NT,
      Wq_pt, bq_pt, Qb, H, 0,
      Ws_pt, bs_pt, Sb, H, 0);
  mgemm<1,1,1,1><<<gP,256,0,stream>>>(P1b, NP,
      Wk_pt, bk_pt, KVb, 256, 0,
      Wv_pt, bv_pt, KVb, 256, H);
  knode3<<<CDIV(NT*32,256),256,0,stream>>>(Qb, KVb, Sb, rowT, degT, srcsT,
                                           Wb_pt, T1b, NT);

  // head: bf16 t2 -> fp32 out
  mgemm<1,0,0,0><<<gT,256,0,stream>>>(T1b, NT,
      W_head, b_head, out, H, 0,
      nullptr, nullptr, nullptr, 0, 0);
}

// Round 7
// 323.429 us; speedup vs baseline: 3.0974x; 1.3725x over previous
//
#include <hip/hip_runtime.h>
#include <math.h>

#define NT 100000
#define NP 50000
#define NE 800000
#define H 128
#define NB 196
#define BCAP 8192

#define CDIV(a,b) (((a)+(b)-1)/(b))

typedef __attribute__((ext_vector_type(8))) short s16x8;
typedef __attribute__((ext_vector_type(4))) short s16x4;
typedef __attribute__((ext_vector_type(4))) unsigned short u16x4;
typedef __attribute__((ext_vector_type(4))) float f32x4;

static __device__ __forceinline__ float dot4(float4 a, float4 b){
  return a.x*b.x + a.y*b.y + a.z*b.z + a.w*b.w;
}
static __device__ __forceinline__ float b2f(unsigned short u){
  union { unsigned int i; float f; } c; c.i = ((unsigned int)u) << 16; return c.f;
}
static __device__ __forceinline__ unsigned short f2b(float f){
  union { float f; unsigned int i; } c; c.f = f;
  unsigned int x = c.i;
  unsigned int r = (x + 0x7fffu + ((x >> 16) & 1u)) >> 16;   // RNE
  return (unsigned short)r;
}
static __device__ __forceinline__ float4 cvt4(ushort4 h){
  return make_float4(b2f(h.x), b2f(h.y), b2f(h.z), b2f(h.w));
}
static __device__ __forceinline__ float4 cvt4u(u16x4 h){
  return make_float4(b2f(h[0]), b2f(h[1]), b2f(h[2]), b2f(h[3]));
}

// ---------- rank-1 helper vectors ----------
__global__ void kvec4(const float* __restrict__ e, const float* __restrict__ be,
    const float* W0, const float* bi0, float* u0, float* w0,
    const float* W1, const float* bi1, float* u1, float* w1,
    const float* W2, const float* bi2, float* u2, float* w2,
    const float* W3, const float* bi3, float* u3, float* w3){
  const float *W, *bi; float *u, *w;
  switch (blockIdx.x){
    case 0: W=W0; bi=bi0; u=u0; w=w0; break;
    case 1: W=W1; bi=bi1; u=u1; w=w1; break;
    case 2: W=W2; bi=bi2; u=u2; w=w2; break;
    default:W=W3; bi=bi3; u=u3; w=w3; break;
  }
  int j = threadIdx.x;
  float su = 0.f, sw = 0.f;
  for (int i = 0; i < H; ++i) {
    float wv = W[i*H + j];
    su += e[i]*wv;
    sw += be[i]*wv;
  }
  u[j] = su;
  w[j] = sw + bi[j];
}

// ---------- MFMA GEMM pieces ----------
static __device__ __forceinline__ void stage_w(const float* __restrict__ W,
    unsigned short* __restrict__ WH, unsigned short* __restrict__ WL, int tid){
  #pragma unroll
  for (int it = 0; it < 16; ++it){
    int gid = it*256 + tid;
    int n  = gid & 127;
    int kg = gid >> 7;
    int k0 = kg*4;
    float w0 = W[(k0+0)*H + n];
    float w1 = W[(k0+1)*H + n];
    float w2 = W[(k0+2)*H + n];
    float w3 = W[(k0+3)*H + n];
    unsigned short h0=f2b(w0), h1=f2b(w1), h2=f2b(w2), h3=f2b(w3);
    s16x4 hv; hv[0]=(short)h0; hv[1]=(short)h1; hv[2]=(short)h2; hv[3]=(short)h3;
    s16x4 lv; lv[0]=(short)f2b(w0-b2f(h0)); lv[1]=(short)f2b(w1-b2f(h1));
              lv[2]=(short)f2b(w2-b2f(h2)); lv[3]=(short)f2b(w3-b2f(h3));
    int base = n*128 + (((kg>>1) ^ (n&15))<<3) + ((kg&1)<<2);
    *(s16x4*)(WH + base) = hv;
    *(s16x4*)(WL + base) = lv;
  }
}

template<bool USE_AL>
static __device__ __forceinline__ void mfma_pass(const s16x8 AH[2][4], const s16x8 AL[2][4],
    const unsigned short* __restrict__ WH, const unsigned short* __restrict__ WL,
    int l15, int l4, f32x4 acc[2][8]){
  #pragma unroll
  for (int g = 0; g < 2; ++g)
    #pragma unroll
    for (int t = 0; t < 8; ++t){ acc[g][t][0]=0.f; acc[g][t][1]=0.f; acc[g][t][2]=0.f; acc[g][t][3]=0.f; }
  #pragma unroll
  for (int s = 0; s < 4; ++s){
    #pragma unroll
    for (int t = 0; t < 8; ++t){
      int n = t*16 + l15;
      int off = n*128 + (((s*4 + l4) ^ l15)<<3);
      s16x8 BH = *(const s16x8*)(WH + off);
      s16x8 BL = *(const s16x8*)(WL + off);
      #pragma unroll
      for (int g = 0; g < 2; ++g){
        acc[g][t] = __builtin_amdgcn_mfma_f32_16x16x32_bf16(AH[g][s], BH, acc[g][t], 0,0,0);
        acc[g][t] = __builtin_amdgcn_mfma_f32_16x16x32_bf16(AH[g][s], BL, acc[g][t], 0,0,0);
        if constexpr (USE_AL)
          acc[g][t] = __builtin_amdgcn_mfma_f32_16x16x32_bf16(AL[g][s], BH, acc[g][t], 0,0,0);
      }
    }
  }
}

#define EPI_WRITE(ACC, BIAS)                                                    \
  {                                                                             \
    float bb[8];                                                                \
    _Pragma("unroll")                                                           \
    for (int t = 0; t < 8; ++t) bb[t] = BIAS[t*16 + l15];                       \
    _Pragma("unroll")                                                           \
    for (int g = 0; g < 2; ++g){                                                \
      _Pragma("unroll")                                                         \
      for (int t = 0; t < 8; ++t){                                              \
        _Pragma("unroll")                                                       \
        for (int r = 0; r < 4; ++r)                                             \
          EPI[w*32 + g*16 + l4*4 + r][t*16 + l15] = ACC[g][t][r] + bb[t];       \
      }                                                                         \
    }                                                                           \
  }

template<int BF>
static __device__ __forceinline__ void epi_store(void* Y, int ld, int of, int row0, int M,
                                                 int tid, const float (*EPI)[132]){
  #pragma unroll
  for (int it = 0; it < 16; ++it){
    int fid = it*256 + tid;
    int r = fid >> 5, c4 = (fid & 31) << 2;
    int grow = row0 + r;
    if (grow < M){
      float4 v = *(const float4*)&EPI[r][c4];
      if constexpr (BF){
        ushort4 hv; hv.x=f2b(v.x); hv.y=f2b(v.y); hv.z=f2b(v.z); hv.w=f2b(v.w);
        *(ushort4*)((unsigned short*)Y + (size_t)grow*ld + of + c4) = hv;
      } else {
        *(float4*)((float*)Y + (size_t)grow*ld + of + c4) = v;
      }
    }
  }
}

static __device__ __forceinline__ void dots_epi(const f32x4 (&acc)[2][8],
    const float* __restrict__ bias, const float* __restrict__ uvec,
    const float* __restrict__ wvec, float2* __restrict__ acout,
    int row0, int M, int w, int l15, int l4){
  float ub[8], wb[8], bb[8];
  #pragma unroll
  for (int t=0;t<8;++t){ ub[t]=uvec[t*16+l15]; wb[t]=wvec[t*16+l15]; bb[t]=bias[t*16+l15]; }
  #pragma unroll
  for (int g=0; g<2; ++g){
    #pragma unroll
    for (int r=0;r<4;++r){
      float pa=0.f, pc=0.f;
      #pragma unroll
      for (int t=0;t<8;++t){ float y=acc[g][t][r]+bb[t]; pa+=y*ub[t]; pc+=y*wb[t]; }
      #pragma unroll
      for (int o=1;o<16;o<<=1){ pa+=__shfl_xor(pa,o); pc+=__shfl_xor(pc,o); }
      int row=row0+w*32+g*16+l4*4+r;
      if (l15==0 && row<M) acout[row]=make_float2(pa,pc);
    }
  }
}

static __device__ __forceinline__ void load_a_f32(const float* __restrict__ X, int M,
    int row0, int w, int l15, int l4, s16x8 AH[2][4], s16x8 AL[2][4]){
  #pragma unroll
  for (int g = 0; g < 2; ++g){
    int row = row0 + w*32 + g*16 + l15;
    const float* xr = X + (size_t)row*H;
    bool ok = row < M;
    #pragma unroll
    for (int s = 0; s < 4; ++s){
      int kb = s*32 + l4*8;
      float4 f0 = ok ? *(const float4*)(xr+kb)   : make_float4(0.f,0.f,0.f,0.f);
      float4 f1 = ok ? *(const float4*)(xr+kb+4) : make_float4(0.f,0.f,0.f,0.f);
      float xs[8] = {f0.x,f0.y,f0.z,f0.w,f1.x,f1.y,f1.z,f1.w};
      s16x8 h, lo;
      #pragma unroll
      for (int e = 0; e < 8; ++e){
        unsigned short hh = f2b(xs[e]);
        h[e]  = (short)hh;
        lo[e] = (short)f2b(xs[e] - b2f(hh));
      }
      AH[g][s] = h; AL[g][s] = lo;
    }
  }
}
static __device__ __forceinline__ void load_a_bf16(const unsigned short* __restrict__ Xb, int M,
    int row0, int w, int l15, int l4, s16x8 AH[2][4]){
  #pragma unroll
  for (int g = 0; g < 2; ++g){
    int row = row0 + w*32 + g*16 + l15;
    const unsigned short* xr = Xb + (size_t)row*H;
    bool ok = row < M;
    #pragma unroll
    for (int s = 0; s < 4; ++s){
      s16x8 h = {0,0,0,0,0,0,0,0};
      if (ok) h = *(const s16x8*)(xr + s*32 + l4*8);
      AH[g][s] = h;
    }
  }
}

// ---------- fused phrase-side GEMM: 4 passes sharing X fragments ----------
__launch_bounds__(256)
__global__ void mgemm_ph(const float* __restrict__ X, int M,
    const float* __restrict__ Wq, const float* __restrict__ bq,
    const float* __restrict__ uk, const float* __restrict__ wk, float2* __restrict__ ac1,
    const float* __restrict__ Ws, const float* __restrict__ bs, unsigned short* __restrict__ S1b,
    const float* __restrict__ Wk, const float* __restrict__ bk,
    const float* __restrict__ uq, const float* __restrict__ wq, float2* __restrict__ ac2,
    const float* __restrict__ Wv, const float* __restrict__ bv, unsigned short* __restrict__ Vb){
  __shared__ __align__(16) char smem[128*132*4];
  unsigned short* WH = (unsigned short*)smem;
  unsigned short* WL = WH + 16384;
  float (*EPI)[132] = (float(*)[132])smem;
  int tid=threadIdx.x, lane=tid&63, w=tid>>6, l15=lane&15, l4=lane>>4;
  int row0 = blockIdx.x*128;

  s16x8 AH[2][4], AL[2][4];
  load_a_f32(X, M, row0, w, l15, l4, AH, AL);

  f32x4 acc[2][8];
  stage_w(Wq, WH, WL, tid); __syncthreads();
  mfma_pass<true>(AH, AL, WH, WL, l15, l4, acc);
  dots_epi(acc, bq, uk, wk, ac1, row0, M, w, l15, l4);
  __syncthreads();
  stage_w(Ws, WH, WL, tid); __syncthreads();
  mfma_pass<true>(AH, AL, WH, WL, l15, l4, acc);
  __syncthreads(); EPI_WRITE(acc, bs); __syncthreads();
  epi_store<1>(S1b, H, 0, row0, M, tid, EPI);
  __syncthreads();
  stage_w(Wk, WH, WL, tid); __syncthreads();
  mfma_pass<true>(AH, AL, WH, WL, l15, l4, acc);
  dots_epi(acc, bk, uq, wq, ac2, row0, M, w, l15, l4);
  __syncthreads();
  stage_w(Wv, WH, WL, tid); __syncthreads();
  mfma_pass<true>(AH, AL, WH, WL, l15, l4, acc);
  __syncthreads(); EPI_WRITE(acc, bv); __syncthreads();
  epi_store<1>(Vb, H, 0, row0, M, tid, EPI);
}

// ---------- generic 1/2-pass GEMM ----------
template<int XB, int B1, int B2, int TWO>
__launch_bounds__(256)
__global__ void mgemm(const void* __restrict__ Xv, int M,
    const float* __restrict__ W1, const float* __restrict__ b1,
    void* __restrict__ Y1, int ld1, int of1,
    const float* __restrict__ W2, const float* __restrict__ b2,
    void* __restrict__ Y2, int ld2, int of2){
  __shared__ __align__(16) char smem[128*132*4];
  unsigned short* WH = (unsigned short*)smem;
  unsigned short* WL = WH + 16384;
  float (*EPI)[132] = (float(*)[132])smem;
  int tid=threadIdx.x, lane=tid&63, w=tid>>6, l15=lane&15, l4=lane>>4;
  int row0 = blockIdx.x*128;

  s16x8 AH[2][4], AL[2][4];
  if constexpr (XB) load_a_bf16((const unsigned short*)Xv, M, row0, w, l15, l4, AH);
  else              load_a_f32((const float*)Xv, M, row0, w, l15, l4, AH, AL);

  stage_w(W1, WH, WL, tid); __syncthreads();
  f32x4 acc[2][8];
  mfma_pass<!XB>(AH, AL, WH, WL, l15, l4, acc);
  __syncthreads();
  EPI_WRITE(acc, b1);
  __syncthreads();
  epi_store<B1>(Y1, ld1, of1, row0, M, tid, EPI);

  if constexpr (TWO){
    __syncthreads();
    stage_w(W2, WH, WL, tid); __syncthreads();
    f32x4 acc2[2][8];
    mfma_pass<!XB>(AH, AL, WH, WL, l15, l4, acc2);
    __syncthreads();
    EPI_WRITE(acc2, b2);
    __syncthreads();
    epi_store<B2>(Y2, ld2, of2, row0, M, tid, EPI);
  }
}

// ---------- passA: bucket-bin edges; LDS histogram + bulk reservation ----------
// GATHER=1: payload = bits(xv[src]); GATHER=0: payload = src
template<int GATHER>
__launch_bounds__(256)
__global__ void passA(const int* __restrict__ dst, const int* __restrict__ src,
                      const float* __restrict__ xv, int shift,
                      int* __restrict__ bcnt, int2* __restrict__ out, int n){
  __shared__ int hist[NB];
  __shared__ int base[NB];
  __shared__ int cur[NB];
  int tid = threadIdx.x;
  for (int i = tid; i < NB; i += 256){ hist[i]=0; cur[i]=0; }
  __syncthreads();
  int e0 = blockIdx.x*2048;
  int d[8], s[8];
  #pragma unroll
  for (int k = 0; k < 8; ++k){
    int i = e0 + k*256 + tid;
    if (i < n){ d[k] = dst[i]; s[k] = src[i]; }
    else d[k] = -1;
  }
  #pragma unroll
  for (int k = 0; k < 8; ++k)
    if (d[k] >= 0) atomicAdd(&hist[d[k]>>shift], 1);
  __syncthreads();
  for (int b = tid; b < NB; b += 256)
    base[b] = hist[b] ? atomicAdd(&bcnt[b], hist[b]) : 0;
  __syncthreads();
  #pragma unroll
  for (int k = 0; k < 8; ++k){
    if (d[k] >= 0){
      int b = d[k] >> shift;
      int loc = atomicAdd(&cur[b], 1);
      int2 rec;
      if constexpr (GATHER) rec.x = __float_as_int(xv[s[k]]);
      else                  rec.x = s[k];
      rec.y = d[k] - (b << shift);
      out[(size_t)b*BCAP + base[b] + loc] = rec;
    }
  }
}

// ---------- passB phrase: per-bucket LDS accumulate of (sum e, sum e*x) ----------
__launch_bounds__(512)
__global__ void passB_ph(const int* __restrict__ bcnt, const int2* __restrict__ sorted,
                         const float2* __restrict__ ac, float2* __restrict__ dsv, int np){
  __shared__ float2 acl[256];
  __shared__ float accx[256];
  __shared__ float accy[256];
  int b = blockIdx.x, tid = threadIdx.x;
  int p0 = b*256;
  if (tid < 256){
    int p = p0 + tid;
    acl[tid] = (p < np) ? ac[p] : make_float2(0.f,0.f);
    accx[tid] = 0.f; accy[tid] = 0.f;
  }
  __syncthreads();
  int n = bcnt[b];
  const int2* e = sorted + (size_t)b*BCAP;
  const float RS = 0.08838834764831845f;
  for (int i = tid; i < n; i += 512){
    int2 ed = e[i];
    float x = __int_as_float(ed.x);
    float2 a = acl[ed.y];
    float ex = __expf((x*a.x + a.y)*RS);
    atomicAdd(&accx[ed.y], ex);
    atomicAdd(&accy[ed.y], ex*x);
  }
  __syncthreads();
  if (tid < 256){
    int p = p0 + tid;
    if (p < np) dsv[p] = make_float2(accx[tid], accy[tid]);
  }
}

// ---------- passB token: per-bucket CSR build (rowptr/deg/srcs) ----------
__launch_bounds__(512)
__global__ void passB_tok(const int* __restrict__ bcnt, const int2* __restrict__ sorted,
                          int* __restrict__ rowptr, int* __restrict__ deg,
                          int* __restrict__ srcs, int ntok){
  __shared__ int cnt[512];
  __shared__ int scn[512];
  __shared__ int cur[512];
  int b = blockIdx.x, tid = threadIdx.x;
  cnt[tid] = 0; cur[tid] = 0;
  __syncthreads();
  int n = bcnt[b];
  const int2* e = sorted + (size_t)b*BCAP;
  for (int i = tid; i < n; i += 512) atomicAdd(&cnt[e[i].y], 1);
  __syncthreads();
  int myc = cnt[tid];
  scn[tid] = myc;
  __syncthreads();
  for (int off = 1; off < 512; off <<= 1){
    int u = (tid >= off) ? scn[tid-off] : 0;
    __syncthreads();
    scn[tid] += u;
    __syncthreads();
  }
  int excl = scn[tid] - myc;
  int tok = b*512 + tid;
  if (tok < ntok){ rowptr[tok] = b*BCAP + excl; deg[tok] = myc; }
  __syncthreads();
  cnt[tid] = excl;            // reuse cnt as exclusive-offset table
  __syncthreads();
  for (int i = tid; i < n; i += 512){
    int2 ed = e[i];
    int pos = cnt[ed.y] + atomicAdd(&cur[ed.y], 1);
    srcs[(size_t)b*BCAP + pos] = ed.x;
  }
}

// ---------- beta gate + combine; OB: bf16 output ----------
template<int OB>
static __device__ __forceinline__ void beta_combine(float4 o, float4 sk,
    const float* __restrict__ Wb, int lane, bool leaky, void* __restrict__ dstRow){
  float4 wb0 = *(const float4*)&Wb[lane*4];
  float4 wb1 = *(const float4*)&Wb[H   + lane*4];
  float4 wb2 = *(const float4*)&Wb[2*H + lane*4];
  float4 dv = make_float4(o.x-sk.x, o.y-sk.y, o.z-sk.z, o.w-sk.w);
  float part = dot4(o,wb0) + dot4(sk,wb1) + dot4(dv,wb2);
  #pragma unroll
  for (int off=1; off<32; off<<=1) part += __shfl_xor(part, off);
  float beta = 1.f/(1.f + __expf(-part));
  float4 r;
  r.x = beta*sk.x + (1.f-beta)*o.x;
  r.y = beta*sk.y + (1.f-beta)*o.y;
  r.z = beta*sk.z + (1.f-beta)*o.z;
  r.w = beta*sk.w + (1.f-beta)*o.w;
  if (leaky){
    r.x = r.x>0.f? r.x : 0.01f*r.x;
    r.y = r.y>0.f? r.y : 0.01f*r.y;
    r.z = r.z>0.f? r.z : 0.01f*r.z;
    r.w = r.w>0.f? r.w : 0.01f*r.w;
  }
  if constexpr (OB){
    ushort4 h; h.x=f2b(r.x); h.y=f2b(r.y); h.z=f2b(r.z); h.w=f2b(r.w);
    *(ushort4*)((unsigned short*)dstRow + lane*4) = h;
  } else {
    *(float4*)((float*)dstRow + lane*4) = r;
  }
}

__global__ void kcomb1(const float2* __restrict__ dsv,
                       const float* __restrict__ uv, const float* __restrict__ wv,
                       const unsigned short* __restrict__ S, const float* __restrict__ Wb,
                       unsigned short* __restrict__ out, int n){
  int gid = (blockIdx.x*blockDim.x + threadIdx.x) >> 5;
  int lane = threadIdx.x & 31;
  if (gid >= n) return;
  float2 ds = dsv[gid];
  float d = ds.x, sv = ds.y;
  float inv = 1.f/(d + 1e-16f);
  float4 u4 = *(const float4*)&uv[lane*4];
  float4 w4 = *(const float4*)&wv[lane*4];
  float4 o = make_float4((sv*u4.x + d*w4.x)*inv, (sv*u4.y + d*w4.y)*inv,
                         (sv*u4.z + d*w4.z)*inv, (sv*u4.w + d*w4.w)*inv);
  u16x4 sh4 = __builtin_nontemporal_load((const u16x4*)(S + (size_t)gid*H + lane*4));
  float4 sk = cvt4u(sh4);
  beta_combine<1>(o, sk, Wb, lane, true, out + (size_t)gid*H);
}

// ---------- tconv2: no-max, 2-way unrolled bf16 V gather ----------
__global__ void knode2(const float* __restrict__ x_tok, const float2* __restrict__ ac,
                       const unsigned short* __restrict__ Vb,
                       const int* __restrict__ rowptr, const int* __restrict__ deg,
                       const int* __restrict__ srcs,
                       const float* __restrict__ us, const float* __restrict__ ws,
                       const float* __restrict__ Wb, unsigned short* __restrict__ out, int n){
  int gid = (blockIdx.x*blockDim.x + threadIdx.x) >> 5;
  int lane = threadIdx.x & 31;
  if (gid >= n) return;
  float xt = x_tok[gid];
  int rp = rowptr[gid], dg = deg[gid];
  const float RS = 0.08838834764831845f;
  float d = 0.f;
  float4 acc = make_float4(0.f,0.f,0.f,0.f);
  int i = 0;
  for (; i+2 <= dg; i += 2){
    int spA = srcs[rp+i], spB = srcs[rp+i+1];
    ushort4 hA = *(const ushort4*)(Vb + (size_t)spA*H + lane*4);
    ushort4 hB = *(const ushort4*)(Vb + (size_t)spB*H + lane*4);
    float2 aA = ac[spA], aB = ac[spB];
    float eA = __expf((xt*aA.x + aA.y)*RS);
    float eB = __expf((xt*aB.x + aB.y)*RS);
    float4 vA = cvt4(hA), vB = cvt4(hB);
    d += eA + eB;
    acc.x += eA*vA.x + eB*vB.x;
    acc.y += eA*vA.y + eB*vB.y;
    acc.z += eA*vA.z + eB*vB.z;
    acc.w += eA*vA.w + eB*vB.w;
  }
  if (i < dg){
    int sp = srcs[rp+i];
    ushort4 hv = *(const ushort4*)(Vb + (size_t)sp*H + lane*4);
    float2 a = ac[sp];
    float e = __expf((xt*a.x + a.y)*RS);
    float4 v = cvt4(hv);
    d += e;
    acc.x += e*v.x; acc.y += e*v.y; acc.z += e*v.z; acc.w += e*v.w;
  }
  float inv = 1.f/(d + 1e-16f);
  float4 o = make_float4(acc.x*inv, acc.y*inv, acc.z*inv, acc.w*inv);
  float4 u4 = *(const float4*)&us[lane*4];
  float4 w4 = *(const float4*)&ws[lane*4];
  float4 sk = make_float4(xt*u4.x+w4.x, xt*u4.y+w4.y, xt*u4.z+w4.z, xt*u4.w+w4.w);
  beta_combine<1>(o, sk, Wb, lane, true, out + (size_t)gid*H);
}

// ---------- tconv3: no-max, 2-way unrolled bf16 KV gather ----------
__global__ void knode3(const unsigned short* __restrict__ Q, const unsigned short* __restrict__ KV,
                       const unsigned short* __restrict__ S,
                       const int* __restrict__ rowptr, const int* __restrict__ deg,
                       const int* __restrict__ srcs,
                       const float* __restrict__ Wb, unsigned short* __restrict__ out, int n){
  int gid = (blockIdx.x*blockDim.x + threadIdx.x) >> 5;
  int lane = threadIdx.x & 31;
  if (gid >= n) return;
  u16x4 qh = __builtin_nontemporal_load((const u16x4*)(Q + (size_t)gid*H + lane*4));
  float4 q = cvt4u(qh);
  int rp = rowptr[gid], dg = deg[gid];
  const float RS = 0.08838834764831845f;
  float d = 0.f;
  float4 acc = make_float4(0.f,0.f,0.f,0.f);
  int i = 0;
  for (; i+2 <= dg; i += 2){
    int spA = srcs[rp+i], spB = srcs[rp+i+1];
    const ushort4* kvA = (const ushort4*)(KV + (size_t)spA*256);
    const ushort4* kvB = (const ushort4*)(KV + (size_t)spB*256);
    ushort4 hkA = kvA[lane], hvA = kvA[32+lane];
    ushort4 hkB = kvB[lane], hvB = kvB[32+lane];
    float psA = dot4(q, cvt4(hkA));
    float psB = dot4(q, cvt4(hkB));
    #pragma unroll
    for (int off=1; off<32; off<<=1){ psA += __shfl_xor(psA,off); psB += __shfl_xor(psB,off); }
    float eA = __expf(psA*RS), eB = __expf(psB*RS);
    float4 vA = cvt4(hvA), vB = cvt4(hvB);
    d += eA + eB;
    acc.x += eA*vA.x + eB*vB.x;
    acc.y += eA*vA.y + eB*vB.y;
    acc.z += eA*vA.z + eB*vB.z;
    acc.w += eA*vA.w + eB*vB.w;
  }
  if (i < dg){
    int sp = srcs[rp+i];
    const ushort4* kvp = (const ushort4*)(KV + (size_t)sp*256);
    ushort4 hk = kvp[lane], hv = kvp[32+lane];
    float ps = dot4(q, cvt4(hk));
    #pragma unroll
    for (int off=1; off<32; off<<=1) ps += __shfl_xor(ps,off);
    float e = __expf(ps*RS);
    float4 v = cvt4(hv);
    d += e;
    acc.x += e*v.x; acc.y += e*v.y; acc.z += e*v.z; acc.w += e*v.w;
  }
  float inv = 1.f/(d + 1e-16f);
  float4 o = make_float4(acc.x*inv, acc.y*inv, acc.z*inv, acc.w*inv);
  u16x4 sh4 = __builtin_nontemporal_load((const u16x4*)(S + (size_t)gid*H + lane*4));
  float4 sk = cvt4u(sh4);
  beta_combine<1>(o, sk, Wb, lane, false, out + (size_t)gid*H);
}

extern "C" void kernel_launch(void* const* d_in, const int* in_sizes, int n_in,
                              void* d_out, int out_size, void* d_ws, size_t ws_size,
                              hipStream_t stream){
  const float* x_token  = (const float*)d_in[0];
  const float* x_phrase = (const float*)d_in[1];
  const float* W_emb    = (const float*)d_in[2];
  const float* b_emb    = (const float*)d_in[3];
  const float* Wq_tp = (const float*)d_in[4];  const float* bq_tp = (const float*)d_in[5];
  const float* Wk_tp = (const float*)d_in[6];  const float* bk_tp = (const float*)d_in[7];
  const float* Wv_tp = (const float*)d_in[8];  const float* bv_tp = (const float*)d_in[9];
  const float* Ws_tp = (const float*)d_in[10]; const float* bs_tp = (const float*)d_in[11];
  const float* Wb_tp = (const float*)d_in[12];
  const float* Wq_pt = (const float*)d_in[13]; const float* bq_pt = (const float*)d_in[14];
  const float* Wk_pt = (const float*)d_in[15]; const float* bk_pt = (const float*)d_in[16];
  const float* Wv_pt = (const float*)d_in[17]; const float* bv_pt = (const float*)d_in[18];
  const float* Ws_pt = (const float*)d_in[19]; const float* bs_pt = (const float*)d_in[20];
  const float* Wb_pt = (const float*)d_in[21];
  const float* W_head = (const float*)d_in[22]; const float* b_head = (const float*)d_in[23];
  const int* src_tp = (const int*)d_in[24];
  const int* dst_tp = (const int*)d_in[25];
  const int* src_pt = (const int*)d_in[26];
  const int* dst_pt = (const int*)d_in[27];
  float* out = (float*)d_out;

  // ---- workspace carve (byte-exact, ~150 MB) ----
  char* base = (char*)d_ws;
  size_t off = 0;
  auto AB = [&](size_t bytes)->void*{ void* p=(void*)(base+off); off += (bytes+15)&~(size_t)15; return p; };
  unsigned short* S1KV = (unsigned short*)AB((size_t)NP*256*2); // S1b [NP][128], later KVb [NP][256]
  unsigned short* P1b  = (unsigned short*)AB((size_t)NP*H*2);
  unsigned short* VQ   = (unsigned short*)AB((size_t)NT*H*2);   // Vb [NP][128] early, Qb [NT][128] later
  unsigned short* Sb   = (unsigned short*)AB((size_t)NT*H*2);
  unsigned short* T1b  = (unsigned short*)AB((size_t)NT*H*2);
  unsigned short* S1b = S1KV;
  unsigned short* KVb = S1KV;
  unsigned short* Vb  = VQ;
  unsigned short* Qb  = VQ;
  float* vecs = (float*)AB(8*H*4);
  float* uk1=vecs, *wk1=vecs+H, *uv1=vecs+2*H, *wv1=vecs+3*H;
  float* uq2=vecs+4*H, *wq2=vecs+5*H, *us2=vecs+6*H, *ws2=vecs+7*H;
  float2* ac1  = (float2*)AB((size_t)NP*8);
  float2* ac2  = (float2*)AB((size_t)NP*8);
  float2* dsv2 = (float2*)AB((size_t)NP*8);
  int2* sortedP = (int2*)AB((size_t)NB*BCAP*8);
  int2* sortedT = (int2*)AB((size_t)NB*BCAP*8);
  int*  srcsT   = (int*)AB((size_t)NB*BCAP*4);
  int* rowT = (int*)AB((size_t)NT*4);
  int* degT = (int*)AB((size_t)NT*4);
  int* bcnt = (int*)AB((size_t)2*NB*4);
  int* bcntP = bcnt, * bcntT = bcnt + NB;
  (void)ws_size; (void)in_sizes; (void)n_in; (void)out_size;

  const int gP = CDIV(NP,128), gT = CDIV(NT,128);
  const int nbA = CDIV(NE,2048);

  kvec4<<<4,H,0,stream>>>(W_emb, b_emb,
      Wk_tp, bk_tp, uk1, wk1,
      Wv_tp, bv_tp, uv1, wv1,
      Wq_pt, bq_pt, uq2, wq2,
      Ws_pt, bs_pt, us2, ws2);

  // bucket-bin both edge lists (no fabric per-edge atomics)
  (void)hipMemsetAsync(bcnt, 0, (size_t)2*NB*4, stream);
  passA<1><<<nbA,256,0,stream>>>(dst_tp, src_tp, x_token, 8, bcntP, sortedP, NE);
  passA<0><<<nbA,256,0,stream>>>(dst_pt, src_pt, nullptr, 9, bcntT, sortedT, NE);

  // token CSR from buckets
  passB_tok<<<NB,512,0,stream>>>(bcntT, sortedT, rowT, degT, srcsT, NT);

  // fused phrase-side GEMMs: q1-dots(ac1), s1->S1b, k2-dots(ac2), v2->Vb
  mgemm_ph<<<gP,256,0,stream>>>(x_phrase, NP,
      Wq_tp, bq_tp, uk1, wk1, ac1,
      Ws_tp, bs_tp, S1b,
      Wk_pt, bk_pt, uq2, wq2, ac2,
      Wv_pt, bv_pt, Vb);

  // tconv1: per-bucket LDS accumulate + combine -> p1 (bf16)
  passB_ph<<<NB,512,0,stream>>>(bcntP, sortedP, ac1, dsv2, NP);
  kcomb1<<<CDIV(NP*32,256),256,0,stream>>>(dsv2, uv1, wv1, S1b, Wb_tp, P1b, NP);

  // tconv2 -> t1 (bf16)
  knode2<<<CDIV(NT*32,256),256,0,stream>>>(x_token, ac2, Vb, rowT, degT, srcsT,
                                           us2, ws2, Wb_pt, T1b, NT);

  // tconv3: q3,s3 from t1; k3,v3 from p1 -> interleaved KV
  mgemm<1,1,1,1><<<gT,256,0,stream>>>(T1b, NT,
      Wq_pt, bq_pt, Qb, H, 0,
      Ws_pt, bs_pt, Sb, H, 0);
  mgemm<1,1,1,1><<<gP,256,0,stream>>>(P1b, NP,
      Wk_pt, bk_pt, KVb, 256, 0,
      Wv_pt, bv_pt, KVb, 256, H);
  knode3<<<CDIV(NT*32,256),256,0,stream>>>(Qb, KVb, Sb, rowT, degT, srcsT,
                                           Wb_pt, T1b, NT);

  // head: bf16 t2 -> fp32 out
  mgemm<1,0,0,0><<<gT,256,0,stream>>>(T1b, NT,
      W_head, b_head, out, H, 0,
      nullptr, nullptr, nullptr, 0, 0);
}